// Round 1
// baseline (1795.455 us; speedup 1.0000x reference)
//
#include <hip/hip_runtime.h>
#include <math.h>

// Problem constants
#define NB   8
#define NSEQ 1024
#define CDIM 1024
#define NH   16
#define HD   64
#define TC   3072

// Workspace layout (float offsets)
//   q : [B][H][N][D]  8*16*1024*64 = 8388608 floats
//   k : same
//   v : same
//   o : [B][N][C]     8388608 floats
//   cs: [N][32] float2 = 65536 floats
#define QOFF ((size_t)0)
#define KOFF ((size_t)8388608)
#define VOFF ((size_t)16777216)
#define OOFF ((size_t)25165824)
#define TOFF ((size_t)33554432)
// total = 33619968 floats = 134.5 MB

// ---------------------------------------------------------------------------
// RoPE cos/sin table: ang[n][p], p=0..31. p even -> (n>>5)*theta[p>>1],
// p odd -> (n&31)*theta[p>>1], theta[t] = 10000^(-t/16).
// ---------------------------------------------------------------------------
__global__ __launch_bounds__(256) void rope_table_k(float* __restrict__ ws) {
  int idx = blockIdx.x * 256 + threadIdx.x;
  if (idx >= NSEQ * 32) return;
  int n = idx >> 5, p = idx & 31;
  int t = p >> 1;
  int pos = (p & 1) ? (n & 31) : (n >> 5);
  float th = (float)pow(10000.0, -(double)t / 16.0);
  float ang = (float)pos * th;
  float2* cs = (float2*)(ws + TOFF);
  cs[idx] = make_float2(cosf(ang), sinf(ang));
}

// ---------------------------------------------------------------------------
// Tiled fp32 GEMM: out[m][c] = sum_k A[m][k] * W[c][k] + bias[c]
// MODE 0: plain store to `out` (M x 1024)
// MODE 1: QKV epilogue: RoPE on q/k, scatter to ws q/k/v in (B,H,N,D)
// Tile 64x64, BK=16, 256 threads, 4x4 microtile.
// ---------------------------------------------------------------------------
template <int MODE>
__global__ __launch_bounds__(256) void gemm_k(
    const float* __restrict__ A, const float* __restrict__ W,
    const float* __restrict__ bias, float* __restrict__ out,
    float* __restrict__ ws, int K) {
  __shared__ float As[16][68];  // [kk][m]
  __shared__ float Bs[16][68];  // [kk][c]
  const int tid = threadIdx.x;
  const int tx = tid & 15, ty = tid >> 4;
  const int m0 = blockIdx.y * 64, c0 = blockIdx.x * 64;
  const int lrow = tid >> 2;       // 0..63
  const int lk4 = (tid & 3) * 4;   // 0,4,8,12
  const float* Arow = A + (size_t)(m0 + lrow) * K + lk4;
  const float* Wrow = W + (size_t)(c0 + lrow) * K + lk4;
  float acc[4][4] = {};

  for (int k0 = 0; k0 < K; k0 += 16) {
    float4 av = *(const float4*)(Arow + k0);
    float4 bv = *(const float4*)(Wrow + k0);
    __syncthreads();
    As[lk4 + 0][lrow] = av.x;
    As[lk4 + 1][lrow] = av.y;
    As[lk4 + 2][lrow] = av.z;
    As[lk4 + 3][lrow] = av.w;
    Bs[lk4 + 0][lrow] = bv.x;
    Bs[lk4 + 1][lrow] = bv.y;
    Bs[lk4 + 2][lrow] = bv.z;
    Bs[lk4 + 3][lrow] = bv.w;
    __syncthreads();
#pragma unroll
    for (int kk = 0; kk < 16; kk++) {
      float a[4], b[4];
      *(float4*)a = *(const float4*)&As[kk][ty * 4];
      *(float4*)b = *(const float4*)&Bs[kk][tx * 4];
#pragma unroll
      for (int i = 0; i < 4; i++)
#pragma unroll
        for (int j = 0; j < 4; j++) acc[i][j] += a[i] * b[j];
    }
  }

  if (MODE == 0) {
#pragma unroll
    for (int i = 0; i < 4; i++) {
      int m = m0 + ty * 4 + i;
      float4 r;
      r.x = acc[i][0] + bias[c0 + tx * 4 + 0];
      r.y = acc[i][1] + bias[c0 + tx * 4 + 1];
      r.z = acc[i][2] + bias[c0 + tx * 4 + 2];
      r.w = acc[i][3] + bias[c0 + tx * 4 + 3];
      *(float4*)&out[(size_t)m * CDIM + c0 + tx * 4] = r;
    }
  } else {
    // Tile columns are head-aligned (64-wide): `which` and `h` uniform.
    const int which = c0 >> 10;          // 0=q 1=k 2=v
    const int h = (c0 & 1023) >> 6;
    float* dst = ws + (which == 0 ? QOFF : (which == 1 ? KOFF : VOFF));
    const float2* cs = (const float2*)(ws + TOFF);
#pragma unroll
    for (int i = 0; i < 4; i++) {
      int m = m0 + ty * 4 + i;
      int b = m >> 10, n = m & 1023;
      float v0 = acc[i][0] + bias[c0 + tx * 4 + 0];
      float v1 = acc[i][1] + bias[c0 + tx * 4 + 1];
      float v2 = acc[i][2] + bias[c0 + tx * 4 + 2];
      float v3 = acc[i][3] + bias[c0 + tx * 4 + 3];
      if (which < 2) {  // RoPE on q,k: pairs (d, d+1), pair index = d/2
        float2 cs0 = cs[n * 32 + tx * 2 + 0];
        float2 cs1 = cs[n * 32 + tx * 2 + 1];
        float t0 = v0 * cs0.x - v1 * cs0.y;
        float t1 = v0 * cs0.y + v1 * cs0.x;
        float t2 = v2 * cs1.x - v3 * cs1.y;
        float t3 = v2 * cs1.y + v3 * cs1.x;
        v0 = t0; v1 = t1; v2 = t2; v3 = t3;
      }
      *(float4*)&dst[(((size_t)b * NH + h) * NSEQ + n) * HD + tx * 4] =
          make_float4(v0, v1, v2, v3);
    }
  }
}

// ---------------------------------------------------------------------------
// Flash attention, fp32. Block: one (b,h), 64 q-rows; KV tiles of 64.
// 256 threads; thread (ty=tid>>4, tx=tid&15) owns 4 q-rows x 4 cols.
// ---------------------------------------------------------------------------
__global__ __launch_bounds__(256) void attn_k(float* __restrict__ ws) {
  __shared__ float Qs[64][68];  // [row][d], pre-scaled
  __shared__ float Kt[64][68];  // [d][key]
  __shared__ float Vs[64][68];  // [key][d]
  __shared__ float Ps[64][68];  // [row][key]
  const int tid = threadIdx.x;
  const int tx = tid & 15, ty = tid >> 4;
  const int bh = blockIdx.y;
  const int n0 = blockIdx.x * 64;
  const float* qg = ws + QOFF + ((size_t)bh * NSEQ + n0) * HD;
  const float* kg = ws + KOFF + (size_t)bh * NSEQ * HD;
  const float* vg = ws + VOFF + (size_t)bh * NSEQ * HD;
  const int lr = tid >> 2;        // 0..63
  const int lc = (tid & 3) * 16;  // 0,16,32,48

#pragma unroll
  for (int ii = 0; ii < 4; ii++) {
    float4 qv = *(const float4*)(qg + lr * HD + lc + ii * 4);
    qv.x *= 0.125f; qv.y *= 0.125f; qv.z *= 0.125f; qv.w *= 0.125f;
    *(float4*)&Qs[lr][lc + ii * 4] = qv;
  }

  float m_run[4], l_run[4], o[4][4];
#pragma unroll
  for (int i = 0; i < 4; i++) {
    m_run[i] = -INFINITY;
    l_run[i] = 0.f;
#pragma unroll
    for (int j = 0; j < 4; j++) o[i][j] = 0.f;
  }

  for (int kt = 0; kt < 16; kt++) {
    __syncthreads();  // previous tile's PV done before overwriting Kt/Vs
#pragma unroll
    for (int ii = 0; ii < 4; ii++) {
      float4 kv = *(const float4*)(kg + (size_t)(kt * 64 + lr) * HD + lc + ii * 4);
      Kt[lc + ii * 4 + 0][lr] = kv.x;
      Kt[lc + ii * 4 + 1][lr] = kv.y;
      Kt[lc + ii * 4 + 2][lr] = kv.z;
      Kt[lc + ii * 4 + 3][lr] = kv.w;
      float4 vv = *(const float4*)(vg + (size_t)(kt * 64 + lr) * HD + lc + ii * 4);
      *(float4*)&Vs[lr][lc + ii * 4] = vv;
    }
    __syncthreads();

    // S = Qs @ Kt  (4x4 per thread)
    float s[4][4] = {};
    for (int kk = 0; kk < 64; kk += 4) {
      float qa[4][4];
#pragma unroll
      for (int i = 0; i < 4; i++)
        *(float4*)qa[i] = *(const float4*)&Qs[ty * 4 + i][kk];
#pragma unroll
      for (int u = 0; u < 4; u++) {
        float b[4];
        *(float4*)b = *(const float4*)&Kt[kk + u][tx * 4];
#pragma unroll
        for (int i = 0; i < 4; i++)
#pragma unroll
          for (int j = 0; j < 4; j++) s[i][j] += qa[i][u] * b[j];
      }
    }

    // online softmax per row (16 lanes share a row via shfl_xor over tx)
#pragma unroll
    for (int i = 0; i < 4; i++) {
      float tm = fmaxf(fmaxf(s[i][0], s[i][1]), fmaxf(s[i][2], s[i][3]));
#pragma unroll
      for (int off = 1; off < 16; off <<= 1)
        tm = fmaxf(tm, __shfl_xor(tm, off, 64));
      float mn = fmaxf(m_run[i], tm);
      float fs = expf(m_run[i] - mn);
      float p[4];
      float ts = 0.f;
#pragma unroll
      for (int j = 0; j < 4; j++) { p[j] = expf(s[i][j] - mn); ts += p[j]; }
#pragma unroll
      for (int off = 1; off < 16; off <<= 1) ts += __shfl_xor(ts, off, 64);
      l_run[i] = l_run[i] * fs + ts;
      m_run[i] = mn;
#pragma unroll
      for (int j = 0; j < 4; j++) o[i][j] *= fs;
      *(float4*)&Ps[ty * 4 + i][tx * 4] = make_float4(p[0], p[1], p[2], p[3]);
    }
    __syncthreads();

    // O += P @ V
    for (int kk = 0; kk < 64; kk += 4) {
      float pa[4][4];
#pragma unroll
      for (int i = 0; i < 4; i++)
        *(float4*)pa[i] = *(const float4*)&Ps[ty * 4 + i][kk];
#pragma unroll
      for (int u = 0; u < 4; u++) {
        float vb[4];
        *(float4*)vb = *(const float4*)&Vs[kk + u][tx * 4];
#pragma unroll
        for (int i = 0; i < 4; i++)
#pragma unroll
          for (int j = 0; j < 4; j++) o[i][j] += pa[i][u] * vb[j];
      }
    }
  }

  const int b = bh >> 4, h = bh & 15;
  float* og = ws + OOFF;
#pragma unroll
  for (int i = 0; i < 4; i++) {
    float inv = 1.0f / l_run[i];
    *(float4*)&og[((size_t)b * NSEQ + n0 + ty * 4 + i) * CDIM + h * HD + tx * 4] =
        make_float4(o[i][0] * inv, o[i][1] * inv, o[i][2] * inv, o[i][3] * inv);
  }
}

// ---------------------------------------------------------------------------
extern "C" void kernel_launch(void* const* d_in, const int* in_sizes, int n_in,
                              void* d_out, int out_size, void* d_ws, size_t ws_size,
                              hipStream_t stream) {
  const float* x      = (const float*)d_in[0];
  const float* wqkv_w = (const float*)d_in[1];
  const float* wqkv_b = (const float*)d_in[2];
  const float* out_w  = (const float*)d_in[3];
  const float* out_b  = (const float*)d_in[4];
  float* out = (float*)d_out;
  float* ws  = (float*)d_ws;

  // 1) RoPE table
  rope_table_k<<<dim3((NSEQ * 32 + 255) / 256), 256, 0, stream>>>(ws);
  // 2) QKV GEMM + bias + RoPE + scatter (M=8192, K=1024, NC=3072)
  gemm_k<1><<<dim3(TC / 64, (NB * NSEQ) / 64), 256, 0, stream>>>(
      x, wqkv_w, wqkv_b, nullptr, ws, CDIM);
  // 3) flash attention -> o (B,N,C)
  attn_k<<<dim3(NSEQ / 64, NB * NH), 256, 0, stream>>>(ws);
  // 4) out GEMM + bias -> d_out (M=8192, K=1024, NC=1024)
  gemm_k<0><<<dim3(CDIM / 64, (NB * NSEQ) / 64), 256, 0, stream>>>(
      ws + OOFF, out_w, out_b, out, ws, CDIM);
}

// Round 2
// 1000.290 us; speedup vs baseline: 1.7949x; 1.7949x over previous
//
#include <hip/hip_runtime.h>
#include <math.h>

// Problem constants
#define NB   8
#define NSEQ 1024
#define CDIM 1024
#define NH   16
#define HD   64
#define TC   3072

typedef unsigned short u16;
typedef __attribute__((ext_vector_type(8))) short bf16x8;
typedef __attribute__((ext_vector_type(4))) float f32x4;

// Workspace layout in u16 (ushort) units:
//   q,k,v  : [B][H][N][D] bf16, 8388608 each
//   xhi,xlo: [8192][1024] bf16 (reused as o_hi/o_lo after QKV GEMM)
//   wqh,wql: [3072][1024] bf16
//   owh,owl: [1024][1024] bf16
//   cs     : float2[1024][32] RoPE table (byte offset CS_B)
#define Q_U   ((size_t)0)
#define K_U   ((size_t)8388608)
#define V_U   ((size_t)16777216)
#define XH_U  ((size_t)25165824)
#define XL_U  ((size_t)33554432)
#define WQH_U ((size_t)41943040)
#define WQL_U ((size_t)45088768)
#define OWH_U ((size_t)48234496)
#define OWL_U ((size_t)49283072)
#define CS_B  ((size_t)100663296)
// total = 100.9 MB (< 134.5 MB proven available)

__device__ inline u16 bf16rne(float f) {
  unsigned int u = __float_as_uint(f);
  u += 0x7FFFu + ((u >> 16) & 1u);
  return (u16)(u >> 16);
}
__device__ inline float bf2f(u16 h) {
  return __uint_as_float(((unsigned int)h) << 16);
}
__device__ inline void gload16(const u16* g, u16* l) {
  __builtin_amdgcn_global_load_lds(
      (const __attribute__((address_space(1))) void*)g,
      (__attribute__((address_space(3))) void*)l, 16, 0, 0);
}

// ---------------------------------------------------------------------------
// RoPE cos/sin table (fp32): cs[n][p], p=0..31.
// ---------------------------------------------------------------------------
__global__ __launch_bounds__(256) void rope_table_k(float2* __restrict__ cs) {
  int idx = blockIdx.x * 256 + threadIdx.x;
  if (idx >= NSEQ * 32) return;
  int n = idx >> 5, p = idx & 31;
  int t = p >> 1;
  int pos = (p & 1) ? (n & 31) : (n >> 5);
  float th = (float)pow(10000.0, -(double)t / 16.0);
  float ang = (float)pos * th;
  cs[idx] = make_float2(cosf(ang), sinf(ang));
}

// ---------------------------------------------------------------------------
// fp32 -> (hi, lo) bf16 split, float4-vectorized
// ---------------------------------------------------------------------------
__global__ __launch_bounds__(256) void split_k(const float* __restrict__ in,
                                               u16* __restrict__ hi,
                                               u16* __restrict__ lo, int n4) {
  int i = blockIdx.x * 256 + threadIdx.x;
  if (i >= n4) return;
  float4 v = ((const float4*)in)[i];
  ushort4 h, l;
  h.x = bf16rne(v.x); l.x = bf16rne(v.x - bf2f(h.x));
  h.y = bf16rne(v.y); l.y = bf16rne(v.y - bf2f(h.y));
  h.z = bf16rne(v.z); l.z = bf16rne(v.z - bf2f(h.z));
  h.w = bf16rne(v.w); l.w = bf16rne(v.w - bf2f(h.w));
  ((ushort4*)hi)[i] = h;
  ((ushort4*)lo)[i] = l;
}

// ---------------------------------------------------------------------------
// Split-bf16 MFMA GEMM: out[m][c] = sum_k A[m][k]*W[c][k] + bias[c]
// A = Ah+Al, W = Bh+Bl (bf16 hi/lo).  acc += Ah*Bh + Ah*Bl + Al*Bh.
// 128x128 tile, BK=32, 256 threads (4 waves, 2x2 of 64x64), m97 structure.
// MODE 0: fp32 store to outF (C=1024).
// MODE 1: QKV epilogue: RoPE on q/k via shfl_xor(1), bf16 scatter (C=3072).
// ---------------------------------------------------------------------------
template <int MODE>
__global__ __launch_bounds__(256, 2) void mgemm_k(
    const u16* __restrict__ Ah, const u16* __restrict__ Al,
    const u16* __restrict__ Bh, const u16* __restrict__ Bl,
    const float* __restrict__ bias, float* __restrict__ outF,
    u16* __restrict__ q, u16* __restrict__ k, u16* __restrict__ v,
    const float2* __restrict__ cs, int K, int C) {
  __shared__ u16 Ahs[128][32];
  __shared__ u16 Als[128][32];
  __shared__ u16 Bhs[128][32];
  __shared__ u16 Bls[128][32];

  const int t = threadIdx.x;
  const int l = t & 63;
  const int w = t >> 6;
  const int wr = w >> 1, wc = w & 1;
  const int lr = l & 15;
  const int lk = (l >> 4) * 8;
  const int m0 = blockIdx.y * 128, c0 = blockIdx.x * 128;

  // staging coords: thread t loads 16B = 8 bf16; issue i covers 64 rows
  const int srow = t >> 2;
  const int skoff = (t & 3) * 8;
  const u16* agA = Ah + (size_t)(m0 + srow) * K + skoff;
  const u16* agAl = Al + (size_t)(m0 + srow) * K + skoff;
  const u16* agB = Bh + (size_t)(c0 + srow) * K + skoff;
  const u16* agBl = Bl + (size_t)(c0 + srow) * K + skoff;
  const size_t rstep = (size_t)64 * K;
  u16* ldA0 = &Ahs[srow][skoff];
  u16* ldA1 = &Ahs[srow + 64][skoff];
  u16* ldAl0 = &Als[srow][skoff];
  u16* ldAl1 = &Als[srow + 64][skoff];
  u16* ldB0 = &Bhs[srow][skoff];
  u16* ldB1 = &Bhs[srow + 64][skoff];
  u16* ldBl0 = &Bls[srow][skoff];
  u16* ldBl1 = &Bls[srow + 64][skoff];

  f32x4 acc[4][4] = {};

  for (int k0 = 0; k0 < K; k0 += 32) {
    __syncthreads();  // previous tile's MFMA reads done
    gload16(agA + k0, ldA0);
    gload16(agA + rstep + k0, ldA1);
    gload16(agAl + k0, ldAl0);
    gload16(agAl + rstep + k0, ldAl1);
    gload16(agB + k0, ldB0);
    gload16(agB + rstep + k0, ldB1);
    gload16(agBl + k0, ldBl0);
    gload16(agBl + rstep + k0, ldBl1);
    __syncthreads();  // vmcnt(0) drained before barrier -> tiles ready

    bf16x8 bh[4], bl[4];
#pragma unroll
    for (int ni = 0; ni < 4; ni++) {
      bh[ni] = *(const bf16x8*)&Bhs[wc * 64 + ni * 16 + lr][lk];
      bl[ni] = *(const bf16x8*)&Bls[wc * 64 + ni * 16 + lr][lk];
    }
#pragma unroll
    for (int mi = 0; mi < 4; mi++) {
      bf16x8 ah = *(const bf16x8*)&Ahs[wr * 64 + mi * 16 + lr][lk];
      bf16x8 al = *(const bf16x8*)&Als[wr * 64 + mi * 16 + lr][lk];
#pragma unroll
      for (int ni = 0; ni < 4; ni++)
        acc[mi][ni] =
            __builtin_amdgcn_mfma_f32_16x16x32_bf16(ah, bh[ni], acc[mi][ni], 0, 0, 0);
#pragma unroll
      for (int ni = 0; ni < 4; ni++)
        acc[mi][ni] =
            __builtin_amdgcn_mfma_f32_16x16x32_bf16(ah, bl[ni], acc[mi][ni], 0, 0, 0);
#pragma unroll
      for (int ni = 0; ni < 4; ni++)
        acc[mi][ni] =
            __builtin_amdgcn_mfma_f32_16x16x32_bf16(al, bh[ni], acc[mi][ni], 0, 0, 0);
    }
  }

  if (MODE == 0) {
#pragma unroll
    for (int mi = 0; mi < 4; mi++) {
      const int row = m0 + wr * 64 + mi * 16 + (l >> 4) * 4;
#pragma unroll
      for (int ni = 0; ni < 4; ni++) {
        const int col = c0 + wc * 64 + ni * 16 + lr;
        const float bv = bias[col];
#pragma unroll
        for (int r = 0; r < 4; r++)
          outF[(size_t)(row + r) * CDIM + col] = acc[mi][ni][r] + bv;
      }
    }
  } else {
    const int which = c0 >> 10;  // 0=q 1=k 2=v (tile never crosses boundary)
    u16* dst = which == 0 ? q : (which == 1 ? k : v);
    const bool dorope = which < 2;
    const int h = ((c0 & 1023) + wc * 64) >> 6;  // wave-uniform head
#pragma unroll
    for (int mi = 0; mi < 4; mi++) {
      const int rbase = m0 + wr * 64 + mi * 16 + (l >> 4) * 4;
#pragma unroll
      for (int ni = 0; ni < 4; ni++) {
        const int d = ni * 16 + lr;  // 0..63 within head
        const float bv = bias[c0 + wc * 64 + d];
#pragma unroll
        for (int r = 0; r < 4; r++) {
          const int m = rbase + r;
          const int b = m >> 10, n = m & 1023;
          float y = acc[mi][ni][r] + bv;
          if (dorope) {
            float yp = __shfl_xor(y, 1, 64);  // partner element of the pair
            float2 csv = cs[n * 32 + (d >> 1)];
            y = (l & 1) ? fmaf(yp, csv.y, y * csv.x)
                        : fmaf(-yp, csv.y, y * csv.x);
          }
          dst[(((size_t)b * NH + h) * NSEQ + n) * HD + d] = bf16rne(y);
        }
      }
    }
  }
}

// ---------------------------------------------------------------------------
// Flash attention, fp32 math over bf16 q/k/v. Writes o as (hi,lo) bf16 pair.
// Block: one (b,h), 64 q-rows; KV tiles of 64. 256 threads, 4x4 microtile.
// ---------------------------------------------------------------------------
__global__ __launch_bounds__(256) void attn_k(const u16* __restrict__ qg0,
                                              const u16* __restrict__ kg0,
                                              const u16* __restrict__ vg0,
                                              u16* __restrict__ ohi,
                                              u16* __restrict__ olo) {
  __shared__ float Qs[64][68];  // [row][d], pre-scaled
  __shared__ float Kt[64][68];  // [d][key]
  __shared__ float Vs[64][68];  // [key][d]
  __shared__ float Ps[64][68];  // [row][key]
  const int tid = threadIdx.x;
  const int tx = tid & 15, ty = tid >> 4;
  const int bh = blockIdx.y;
  const int n0 = blockIdx.x * 64;
  const u16* qg = qg0 + ((size_t)bh * NSEQ + n0) * HD;
  const u16* kg = kg0 + (size_t)bh * NSEQ * HD;
  const u16* vg = vg0 + (size_t)bh * NSEQ * HD;
  const int lr = tid >> 2;
  const int lc = (tid & 3) * 16;

#pragma unroll
  for (int ii = 0; ii < 4; ii++) {
    ushort4 qv = *(const ushort4*)(qg + lr * HD + lc + ii * 4);
    Qs[lr][lc + ii * 4 + 0] = bf2f(qv.x) * 0.125f;
    Qs[lr][lc + ii * 4 + 1] = bf2f(qv.y) * 0.125f;
    Qs[lr][lc + ii * 4 + 2] = bf2f(qv.z) * 0.125f;
    Qs[lr][lc + ii * 4 + 3] = bf2f(qv.w) * 0.125f;
  }

  float m_run[4], l_run[4], o[4][4];
#pragma unroll
  for (int i = 0; i < 4; i++) {
    m_run[i] = -INFINITY;
    l_run[i] = 0.f;
#pragma unroll
    for (int j = 0; j < 4; j++) o[i][j] = 0.f;
  }

  for (int kt = 0; kt < 16; kt++) {
    __syncthreads();
#pragma unroll
    for (int ii = 0; ii < 4; ii++) {
      ushort4 kv = *(const ushort4*)(kg + (size_t)(kt * 64 + lr) * HD + lc + ii * 4);
      Kt[lc + ii * 4 + 0][lr] = bf2f(kv.x);
      Kt[lc + ii * 4 + 1][lr] = bf2f(kv.y);
      Kt[lc + ii * 4 + 2][lr] = bf2f(kv.z);
      Kt[lc + ii * 4 + 3][lr] = bf2f(kv.w);
      ushort4 vv = *(const ushort4*)(vg + (size_t)(kt * 64 + lr) * HD + lc + ii * 4);
      Vs[lr][lc + ii * 4 + 0] = bf2f(vv.x);
      Vs[lr][lc + ii * 4 + 1] = bf2f(vv.y);
      Vs[lr][lc + ii * 4 + 2] = bf2f(vv.z);
      Vs[lr][lc + ii * 4 + 3] = bf2f(vv.w);
    }
    __syncthreads();

    float s[4][4] = {};
    for (int kk = 0; kk < 64; kk += 4) {
      float qa[4][4];
#pragma unroll
      for (int i = 0; i < 4; i++)
        *(float4*)qa[i] = *(const float4*)&Qs[ty * 4 + i][kk];
#pragma unroll
      for (int u = 0; u < 4; u++) {
        float b[4];
        *(float4*)b = *(const float4*)&Kt[kk + u][tx * 4];
#pragma unroll
        for (int i = 0; i < 4; i++)
#pragma unroll
          for (int j = 0; j < 4; j++) s[i][j] += qa[i][u] * b[j];
      }
    }

#pragma unroll
    for (int i = 0; i < 4; i++) {
      float tm = fmaxf(fmaxf(s[i][0], s[i][1]), fmaxf(s[i][2], s[i][3]));
#pragma unroll
      for (int off = 1; off < 16; off <<= 1)
        tm = fmaxf(tm, __shfl_xor(tm, off, 64));
      float mn = fmaxf(m_run[i], tm);
      float fs = expf(m_run[i] - mn);
      float p[4];
      float ts = 0.f;
#pragma unroll
      for (int j = 0; j < 4; j++) { p[j] = expf(s[i][j] - mn); ts += p[j]; }
#pragma unroll
      for (int off = 1; off < 16; off <<= 1) ts += __shfl_xor(ts, off, 64);
      l_run[i] = l_run[i] * fs + ts;
      m_run[i] = mn;
#pragma unroll
      for (int j = 0; j < 4; j++) o[i][j] *= fs;
      *(float4*)&Ps[ty * 4 + i][tx * 4] = make_float4(p[0], p[1], p[2], p[3]);
    }
    __syncthreads();

    for (int kk = 0; kk < 64; kk += 4) {
      float pa[4][4];
#pragma unroll
      for (int i = 0; i < 4; i++)
        *(float4*)pa[i] = *(const float4*)&Ps[ty * 4 + i][kk];
#pragma unroll
      for (int u = 0; u < 4; u++) {
        float vb[4];
        *(float4*)vb = *(const float4*)&Vs[kk + u][tx * 4];
#pragma unroll
        for (int i = 0; i < 4; i++)
#pragma unroll
          for (int j = 0; j < 4; j++) o[i][j] += pa[i][u] * vb[j];
      }
    }
  }

  const int b = bh >> 4, h = bh & 15;
#pragma unroll
  for (int i = 0; i < 4; i++) {
    const float inv = 1.0f / l_run[i];
    const size_t m = (size_t)b * NSEQ + n0 + ty * 4 + i;
    ushort4 hv, lv;
    float ov;
    ov = o[i][0] * inv; hv.x = bf16rne(ov); lv.x = bf16rne(ov - bf2f(hv.x));
    ov = o[i][1] * inv; hv.y = bf16rne(ov); lv.y = bf16rne(ov - bf2f(hv.y));
    ov = o[i][2] * inv; hv.z = bf16rne(ov); lv.z = bf16rne(ov - bf2f(hv.z));
    ov = o[i][3] * inv; hv.w = bf16rne(ov); lv.w = bf16rne(ov - bf2f(hv.w));
    *(ushort4*)&ohi[m * CDIM + h * HD + tx * 4] = hv;
    *(ushort4*)&olo[m * CDIM + h * HD + tx * 4] = lv;
  }
}

// ---------------------------------------------------------------------------
extern "C" void kernel_launch(void* const* d_in, const int* in_sizes, int n_in,
                              void* d_out, int out_size, void* d_ws, size_t ws_size,
                              hipStream_t stream) {
  const float* x      = (const float*)d_in[0];
  const float* wqkv_w = (const float*)d_in[1];
  const float* wqkv_b = (const float*)d_in[2];
  const float* out_w  = (const float*)d_in[3];
  const float* out_b  = (const float*)d_in[4];
  float* out = (float*)d_out;
  u16* ws = (u16*)d_ws;
  float2* cs = (float2*)((char*)d_ws + CS_B);

  // 1) RoPE table + input/weight hi-lo splits
  rope_table_k<<<dim3((NSEQ * 32 + 255) / 256), 256, 0, stream>>>(cs);
  split_k<<<dim3(8192), 256, 0, stream>>>(x, ws + XH_U, ws + XL_U, 2097152);
  split_k<<<dim3(3072), 256, 0, stream>>>(wqkv_w, ws + WQH_U, ws + WQL_U, 786432);
  split_k<<<dim3(1024), 256, 0, stream>>>(out_w, ws + OWH_U, ws + OWL_U, 262144);

  // 2) QKV GEMM (split-bf16 MFMA) + bias + RoPE + bf16 scatter
  mgemm_k<1><<<dim3(TC / 128, (NB * NSEQ) / 128), 256, 0, stream>>>(
      ws + XH_U, ws + XL_U, ws + WQH_U, ws + WQL_U, wqkv_b, nullptr,
      ws + Q_U, ws + K_U, ws + V_U, cs, CDIM, TC);

  // 3) flash attention (fp32 over bf16) -> o as hi/lo bf16 (reuses x region)
  attn_k<<<dim3(NSEQ / 64, NB * NH), 256, 0, stream>>>(
      ws + Q_U, ws + K_U, ws + V_U, ws + XH_U, ws + XL_U);

  // 4) out GEMM (split-bf16 MFMA) + bias -> fp32 d_out
  mgemm_k<0><<<dim3(CDIM / 128, (NB * NSEQ) / 128), 256, 0, stream>>>(
      ws + XH_U, ws + XL_U, ws + OWH_U, ws + OWL_U, out_b, out,
      nullptr, nullptr, nullptr, cs, CDIM, CDIM);
}

// Round 3
// 390.768 us; speedup vs baseline: 4.5947x; 2.5598x over previous
//
#include <hip/hip_runtime.h>
#include <math.h>

// Problem constants
#define NB   8
#define NSEQ 1024
#define CDIM 1024
#define NH   16
#define HD   64
#define TC   3072

typedef unsigned short u16;
typedef __attribute__((ext_vector_type(8))) short bf16x8;
typedef __attribute__((ext_vector_type(8))) unsigned short ushort8;
typedef __attribute__((ext_vector_type(4))) float f32x4;

// Workspace layout in u16 (ushort) units:
//   q,k    : [B][H][N][D] bf16, 8388608 each
//   vT     : [B][H][D][N] bf16 (transposed for PV B-frags)
//   xhi,xlo: [8192][1024] bf16 (reused as o_hi/o_lo after QKV GEMM)
//   wqh,wql: [3072][1024] bf16 ; owh,owl: [1024][1024] bf16
//   cs     : float2[1024][32] RoPE table (byte offset CS_B)
#define Q_U   ((size_t)0)
#define K_U   ((size_t)8388608)
#define V_U   ((size_t)16777216)
#define XH_U  ((size_t)25165824)
#define XL_U  ((size_t)33554432)
#define WQH_U ((size_t)41943040)
#define WQL_U ((size_t)45088768)
#define OWH_U ((size_t)48234496)
#define OWL_U ((size_t)49283072)
#define CS_B  ((size_t)100663296)

__device__ inline u16 bf16rne(float f) {
  unsigned int u = __float_as_uint(f);
  u += 0x7FFFu + ((u >> 16) & 1u);
  return (u16)(u >> 16);
}
__device__ inline float bf2f(u16 h) {
  return __uint_as_float(((unsigned int)h) << 16);
}
__device__ inline void gload16(const u16* g, u16* l) {
  __builtin_amdgcn_global_load_lds(
      (const __attribute__((address_space(1))) void*)g,
      (__attribute__((address_space(3))) void*)l, 16, 0, 0);
}

// ---------------------------------------------------------------------------
__global__ __launch_bounds__(256) void rope_table_k(float2* __restrict__ cs) {
  int idx = blockIdx.x * 256 + threadIdx.x;
  if (idx >= NSEQ * 32) return;
  int n = idx >> 5, p = idx & 31;
  int t = p >> 1;
  int pos = (p & 1) ? (n & 31) : (n >> 5);
  float th = (float)pow(10000.0, -(double)t / 16.0);
  float ang = (float)pos * th;
  cs[idx] = make_float2(cosf(ang), sinf(ang));
}

// ---------------------------------------------------------------------------
__global__ __launch_bounds__(256) void split_k(const float* __restrict__ in,
                                               u16* __restrict__ hi,
                                               u16* __restrict__ lo, int n4) {
  int i = blockIdx.x * 256 + threadIdx.x;
  if (i >= n4) return;
  float4 v = ((const float4*)in)[i];
  ushort4 h, l;
  h.x = bf16rne(v.x); l.x = bf16rne(v.x - bf2f(h.x));
  h.y = bf16rne(v.y); l.y = bf16rne(v.y - bf2f(h.y));
  h.z = bf16rne(v.z); l.z = bf16rne(v.z - bf2f(h.z));
  h.w = bf16rne(v.w); l.w = bf16rne(v.w - bf2f(h.w));
  ((ushort4*)hi)[i] = h;
  ((ushort4*)lo)[i] = l;
}

// ---------------------------------------------------------------------------
// Split-bf16 MFMA GEMM (m97 structure). MODE 0: fp32 out. MODE 1: QKV
// epilogue (RoPE on q/k, bf16 scatter; v stored TRANSPOSED [bh][d][n]).
// ---------------------------------------------------------------------------
template <int MODE>
__global__ __launch_bounds__(256, 2) void mgemm_k(
    const u16* __restrict__ Ah, const u16* __restrict__ Al,
    const u16* __restrict__ Bh, const u16* __restrict__ Bl,
    const float* __restrict__ bias, float* __restrict__ outF,
    u16* __restrict__ q, u16* __restrict__ k, u16* __restrict__ v,
    const float2* __restrict__ cs, int K, int C) {
  __shared__ u16 Ahs[128][32];
  __shared__ u16 Als[128][32];
  __shared__ u16 Bhs[128][32];
  __shared__ u16 Bls[128][32];

  const int t = threadIdx.x;
  const int l = t & 63;
  const int w = t >> 6;
  const int wr = w >> 1, wc = w & 1;
  const int lr = l & 15;
  const int lk = (l >> 4) * 8;
  const int m0 = blockIdx.y * 128, c0 = blockIdx.x * 128;

  const int srow = t >> 2;
  const int skoff = (t & 3) * 8;
  const u16* agA = Ah + (size_t)(m0 + srow) * K + skoff;
  const u16* agAl = Al + (size_t)(m0 + srow) * K + skoff;
  const u16* agB = Bh + (size_t)(c0 + srow) * K + skoff;
  const u16* agBl = Bl + (size_t)(c0 + srow) * K + skoff;
  const size_t rstep = (size_t)64 * K;
  u16* ldA0 = &Ahs[srow][skoff];
  u16* ldA1 = &Ahs[srow + 64][skoff];
  u16* ldAl0 = &Als[srow][skoff];
  u16* ldAl1 = &Als[srow + 64][skoff];
  u16* ldB0 = &Bhs[srow][skoff];
  u16* ldB1 = &Bhs[srow + 64][skoff];
  u16* ldBl0 = &Bls[srow][skoff];
  u16* ldBl1 = &Bls[srow + 64][skoff];

  f32x4 acc[4][4] = {};

  for (int k0 = 0; k0 < K; k0 += 32) {
    __syncthreads();
    gload16(agA + k0, ldA0);
    gload16(agA + rstep + k0, ldA1);
    gload16(agAl + k0, ldAl0);
    gload16(agAl + rstep + k0, ldAl1);
    gload16(agB + k0, ldB0);
    gload16(agB + rstep + k0, ldB1);
    gload16(agBl + k0, ldBl0);
    gload16(agBl + rstep + k0, ldBl1);
    __syncthreads();

    bf16x8 bh[4], bl[4];
#pragma unroll
    for (int ni = 0; ni < 4; ni++) {
      bh[ni] = *(const bf16x8*)&Bhs[wc * 64 + ni * 16 + lr][lk];
      bl[ni] = *(const bf16x8*)&Bls[wc * 64 + ni * 16 + lr][lk];
    }
#pragma unroll
    for (int mi = 0; mi < 4; mi++) {
      bf16x8 ah = *(const bf16x8*)&Ahs[wr * 64 + mi * 16 + lr][lk];
      bf16x8 al = *(const bf16x8*)&Als[wr * 64 + mi * 16 + lr][lk];
#pragma unroll
      for (int ni = 0; ni < 4; ni++)
        acc[mi][ni] =
            __builtin_amdgcn_mfma_f32_16x16x32_bf16(ah, bh[ni], acc[mi][ni], 0, 0, 0);
#pragma unroll
      for (int ni = 0; ni < 4; ni++)
        acc[mi][ni] =
            __builtin_amdgcn_mfma_f32_16x16x32_bf16(ah, bl[ni], acc[mi][ni], 0, 0, 0);
#pragma unroll
      for (int ni = 0; ni < 4; ni++)
        acc[mi][ni] =
            __builtin_amdgcn_mfma_f32_16x16x32_bf16(al, bh[ni], acc[mi][ni], 0, 0, 0);
    }
  }

  if (MODE == 0) {
#pragma unroll
    for (int mi = 0; mi < 4; mi++) {
      const int row = m0 + wr * 64 + mi * 16 + (l >> 4) * 4;
#pragma unroll
      for (int ni = 0; ni < 4; ni++) {
        const int col = c0 + wc * 64 + ni * 16 + lr;
        const float bv = bias[col];
#pragma unroll
        for (int r = 0; r < 4; r++)
          outF[(size_t)(row + r) * CDIM + col] = acc[mi][ni][r] + bv;
      }
    }
  } else {
    const int which = c0 >> 10;  // 0=q 1=k 2=v
    u16* dst = which == 0 ? q : (which == 1 ? k : v);
    const bool dorope = which < 2;
    const int h = ((c0 & 1023) + wc * 64) >> 6;
#pragma unroll
    for (int mi = 0; mi < 4; mi++) {
      const int rbase = m0 + wr * 64 + mi * 16 + (l >> 4) * 4;
#pragma unroll
      for (int ni = 0; ni < 4; ni++) {
        const int d = ni * 16 + lr;
        const float bv = bias[c0 + wc * 64 + d];
#pragma unroll
        for (int r = 0; r < 4; r++) {
          const int m = rbase + r;
          const int b = m >> 10, n = m & 1023;
          float y = acc[mi][ni][r] + bv;
          if (dorope) {
            float yp = __shfl_xor(y, 1, 64);
            float2 csv = cs[n * 32 + (d >> 1)];
            y = (l & 1) ? fmaf(yp, csv.y, y * csv.x)
                        : fmaf(-yp, csv.y, y * csv.x);
            dst[(((size_t)b * NH + h) * NSEQ + n) * HD + d] = bf16rne(y);
          } else {
            // v: transposed store [bh][d][n]
            dst[(((size_t)b * NH + h) * HD + d) * NSEQ + n] = bf16rne(y);
          }
        }
      }
    }
  }
}

// ---------------------------------------------------------------------------
// MFMA flash attention. Block = one (b,h) x 64 q-rows; 4 waves x 16 rows.
// K tile [key][d], V^T tile [d][key] staged via global_load_lds with
// pre-swizzled source (XOR blk ^= row&7 on 16B blocks); per-wave P buffer
// swizzled the same way. Online softmax via 4-stage shfl_xor over 16 lanes.
// ---------------------------------------------------------------------------
__global__ __launch_bounds__(256) void attn_k(const u16* __restrict__ qg0,
                                              const u16* __restrict__ kg0,
                                              const u16* __restrict__ vtg0,
                                              u16* __restrict__ ohi,
                                              u16* __restrict__ olo) {
  __shared__ __align__(16) u16 Ks[4096];      // 64 keys x 64 d (swizzled)
  __shared__ __align__(16) u16 Vt[4096];      // 64 d x 64 keys (swizzled)
  __shared__ __align__(16) u16 Ps[4][1024];   // per-wave 16 q x 64 keys (swz)
  const int t = threadIdx.x;
  const int l = t & 63, w = t >> 6;
  const int lr = l & 15, lg = l >> 4;
  const int bh = blockIdx.x;
  const int n0 = blockIdx.y * 64;

  // Hoist Q A-fragments (row = w*16 + lr, k-chunks c*32 + lg*8), scale 1/8.
  bf16x8 qf[2];
  {
    const u16* qp = qg0 + ((size_t)bh * NSEQ + n0 + w * 16 + lr) * HD + lg * 8;
#pragma unroll
    for (int c = 0; c < 2; c++) {
      ushort8 raw = *(const ushort8*)(qp + c * 32);
      bf16x8 o;
#pragma unroll
      for (int j = 0; j < 8; j++) o[j] = (short)bf16rne(bf2f(raw[j]) * 0.125f);
      qf[c] = o;
    }
  }

  // Staging: 2 issues x 256 threads x 16B per tile for each of K, Vt.
  // LDS linear pos n_i -> row = n_i>>3, blk = n_i&7; fetch global column
  // block (blk ^ (row&7)) so LDS holds the XOR-swizzled layout.
  const int r0 = t >> 3, b0 = (t & 7) ^ (r0 & 7);
  const int r1 = (256 + t) >> 3, b1 = ((256 + t) & 7) ^ (r1 & 7);
  const u16* kgb = kg0 + (size_t)bh * NSEQ * HD;
  const u16* vgb = vtg0 + (size_t)bh * HD * NSEQ;
  const u16* kga0 = kgb + r0 * 64 + b0 * 8;
  const u16* kga1 = kgb + r1 * 64 + b1 * 8;
  const u16* vga0 = vgb + r0 * 1024 + b0 * 8;
  const u16* vga1 = vgb + r1 * 1024 + b1 * 8;
  u16* ksd0 = Ks + (size_t)t * 8;
  u16* ksd1 = Ks + (size_t)(256 + t) * 8;
  u16* vtd0 = Vt + (size_t)t * 8;
  u16* vtd1 = Vt + (size_t)(256 + t) * 8;

  float m_run[4], l_run[4];
  f32x4 oa[4] = {};
#pragma unroll
  for (int r = 0; r < 4; r++) { m_run[r] = -INFINITY; l_run[r] = 0.f; }

  for (int kt = 0; kt < 16; kt++) {
    __syncthreads();  // prior tile's LDS reads complete
    gload16(kga0 + kt * 4096, ksd0);
    gload16(kga1 + kt * 4096, ksd1);
    gload16(vga0 + kt * 64, vtd0);
    gload16(vga1 + kt * 64, vtd1);
    __syncthreads();  // staging drained (vmcnt(0) before barrier)

    // S = Q K^T : rows = q (lg*4+r), cols = key (ni*16 + lr)
    f32x4 s[4] = {};
#pragma unroll
    for (int c = 0; c < 2; c++) {
#pragma unroll
      for (int ni = 0; ni < 4; ni++) {
        const int kr = ni * 16 + lr;
        bf16x8 kf = *(const bf16x8*)&Ks[kr * 64 + (((c * 4 + lg) ^ (kr & 7)) * 8)];
        s[ni] = __builtin_amdgcn_mfma_f32_16x16x32_bf16(qf[c], kf, s[ni], 0, 0, 0);
      }
    }

    // Online softmax per q-row; 16 col-lanes reduce via shfl_xor 1,2,4,8.
#pragma unroll
    for (int r = 0; r < 4; r++) {
      float tm = fmaxf(fmaxf(s[0][r], s[1][r]), fmaxf(s[2][r], s[3][r]));
      tm = fmaxf(tm, __shfl_xor(tm, 1, 64));
      tm = fmaxf(tm, __shfl_xor(tm, 2, 64));
      tm = fmaxf(tm, __shfl_xor(tm, 4, 64));
      tm = fmaxf(tm, __shfl_xor(tm, 8, 64));
      const float mn = fmaxf(m_run[r], tm);
      const float fs = __expf(m_run[r] - mn);
      m_run[r] = mn;
      float p[4], ts = 0.f;
#pragma unroll
      for (int ni = 0; ni < 4; ni++) { p[ni] = __expf(s[ni][r] - mn); ts += p[ni]; }
      ts += __shfl_xor(ts, 1, 64);
      ts += __shfl_xor(ts, 2, 64);
      ts += __shfl_xor(ts, 4, 64);
      ts += __shfl_xor(ts, 8, 64);
      l_run[r] = l_run[r] * fs + ts;
#pragma unroll
      for (int ni = 0; ni < 4; ni++) oa[ni][r] *= fs;
      const int prow = lg * 4 + r;
      const int sw = prow & 7;
#pragma unroll
      for (int ni = 0; ni < 4; ni++)
        Ps[w][prow * 64 + (((ni * 2 + (lr >> 3)) ^ sw) * 8) + (lr & 7)] =
            bf16rne(p[ni]);
    }
    __syncthreads();  // P visible to own wave (and K/Vt reads done)

    // O += P V : A-frag = P[lr][c*32+lg*8], B-frag = Vt[d][c*32+lg*8]
#pragma unroll
    for (int c = 0; c < 2; c++) {
      bf16x8 pa = *(const bf16x8*)&Ps[w][lr * 64 + (((c * 4 + lg) ^ (lr & 7)) * 8)];
#pragma unroll
      for (int ni = 0; ni < 4; ni++) {
        const int dr = ni * 16 + lr;
        bf16x8 vf = *(const bf16x8*)&Vt[dr * 64 + (((c * 4 + lg) ^ (dr & 7)) * 8)];
        oa[ni] = __builtin_amdgcn_mfma_f32_16x16x32_bf16(pa, vf, oa[ni], 0, 0, 0);
      }
    }
  }

  const int b = bh >> 4, h = bh & 15;
#pragma unroll
  for (int r = 0; r < 4; r++) {
    const float inv = 1.0f / l_run[r];
    const size_t n = n0 + w * 16 + lg * 4 + r;
    const size_t base = ((size_t)b * NSEQ + n) * CDIM + h * HD;
#pragma unroll
    for (int ni = 0; ni < 4; ni++) {
      const float ov = oa[ni][r] * inv;
      const u16 hv = bf16rne(ov);
      ohi[base + ni * 16 + lr] = hv;
      olo[base + ni * 16 + lr] = bf16rne(ov - bf2f(hv));
    }
  }
}

// ---------------------------------------------------------------------------
extern "C" void kernel_launch(void* const* d_in, const int* in_sizes, int n_in,
                              void* d_out, int out_size, void* d_ws, size_t ws_size,
                              hipStream_t stream) {
  const float* x      = (const float*)d_in[0];
  const float* wqkv_w = (const float*)d_in[1];
  const float* wqkv_b = (const float*)d_in[2];
  const float* out_w  = (const float*)d_in[3];
  const float* out_b  = (const float*)d_in[4];
  float* out = (float*)d_out;
  u16* ws = (u16*)d_ws;
  float2* cs = (float2*)((char*)d_ws + CS_B);

  rope_table_k<<<dim3((NSEQ * 32 + 255) / 256), 256, 0, stream>>>(cs);
  split_k<<<dim3(8192), 256, 0, stream>>>(x, ws + XH_U, ws + XL_U, 2097152);
  split_k<<<dim3(3072), 256, 0, stream>>>(wqkv_w, ws + WQH_U, ws + WQL_U, 786432);
  split_k<<<dim3(1024), 256, 0, stream>>>(out_w, ws + OWH_U, ws + OWL_U, 262144);

  mgemm_k<1><<<dim3(TC / 128, (NB * NSEQ) / 128), 256, 0, stream>>>(
      ws + XH_U, ws + XL_U, ws + WQH_U, ws + WQL_U, wqkv_b, nullptr,
      ws + Q_U, ws + K_U, ws + V_U, cs, CDIM, TC);

  // grid: x = bh (XCD = bh%8 -> each XCD's K/V set ~4MB = its L2), y = qtile
  attn_k<<<dim3(NB * NH, NSEQ / 64), 256, 0, stream>>>(
      ws + Q_U, ws + K_U, ws + V_U, ws + XH_U, ws + XL_U);

  mgemm_k<0><<<dim3(CDIM / 128, (NB * NSEQ) / 128), 256, 0, stream>>>(
      ws + XH_U, ws + XL_U, ws + OWH_U, ws + OWL_U, out_b, out,
      nullptr, nullptr, nullptr, cs, CDIM, CDIM);
}

// Round 4
// 312.004 us; speedup vs baseline: 5.7546x; 1.2524x over previous
//
#include <hip/hip_runtime.h>
#include <math.h>

// Problem constants
#define NB   8
#define NSEQ 1024
#define CDIM 1024
#define NH   16
#define HD   64
#define TC   3072

typedef unsigned short u16;
typedef __attribute__((ext_vector_type(8))) short bf16x8;
typedef __attribute__((ext_vector_type(8))) _Float16 f16x8;
typedef __attribute__((ext_vector_type(8))) unsigned short ushort8;
typedef __attribute__((ext_vector_type(4))) float f32x4;

// Workspace layout in u16 units:
//   q,k    : [B][H][N][D] bf16
//   vT     : [B][H][D][N] bf16
//   xh     : [8192][1024] fp16 (x; later overwritten by o fp16)
//   wqh,wql: [3072][1024] fp16 hi/lo ; owh,owl: [1024][1024] fp16 hi/lo
//   cs     : float2[1024][32] RoPE table (byte offset CS_B)
#define Q_U   ((size_t)0)
#define K_U   ((size_t)8388608)
#define V_U   ((size_t)16777216)
#define XH_U  ((size_t)25165824)
#define WQH_U ((size_t)41943040)
#define WQL_U ((size_t)45088768)
#define OWH_U ((size_t)48234496)
#define OWL_U ((size_t)49283072)
#define CS_B  ((size_t)100663296)

__device__ inline u16 bf16rne(float f) {
  unsigned int u = __float_as_uint(f);
  u += 0x7FFFu + ((u >> 16) & 1u);
  return (u16)(u >> 16);
}
__device__ inline float bf2f(u16 h) {
  return __uint_as_float(((unsigned int)h) << 16);
}
__device__ inline u16 f16b(float f) {
  union { _Float16 h; u16 u; } c;
  c.h = (_Float16)f;
  return c.u;
}
__device__ inline void gload16(const u16* g, u16* l) {
  __builtin_amdgcn_global_load_lds(
      (const __attribute__((address_space(1))) void*)g,
      (__attribute__((address_space(3))) void*)l, 16, 0, 0);
}

// ---------------------------------------------------------------------------
__global__ __launch_bounds__(256) void rope_table_k(float2* __restrict__ cs) {
  int idx = blockIdx.x * 256 + threadIdx.x;
  if (idx >= NSEQ * 32) return;
  int n = idx >> 5, p = idx & 31;
  int t = p >> 1;
  int pos = (p & 1) ? (n & 31) : (n >> 5);
  float th = (float)pow(10000.0, -(double)t / 16.0);
  float ang = (float)pos * th;
  cs[idx] = make_float2(cosf(ang), sinf(ang));
}

// ---------------------------------------------------------------------------
// fp32 -> fp16 (hi only)
__global__ __launch_bounds__(256) void cvt16_k(const float* __restrict__ in,
                                               u16* __restrict__ hi, int n4) {
  int i = blockIdx.x * 256 + threadIdx.x;
  if (i >= n4) return;
  float4 v = ((const float4*)in)[i];
  ushort4 h;
  h.x = f16b(v.x); h.y = f16b(v.y); h.z = f16b(v.z); h.w = f16b(v.w);
  ((ushort4*)hi)[i] = h;
}

// fp32 -> (hi, lo) fp16 split (for weights)
__global__ __launch_bounds__(256) void splitw_k(const float* __restrict__ in,
                                                u16* __restrict__ hi,
                                                u16* __restrict__ lo, int n4) {
  int i = blockIdx.x * 256 + threadIdx.x;
  if (i >= n4) return;
  float4 v = ((const float4*)in)[i];
  ushort4 h, l;
  union { _Float16 h; u16 u; } c;
  c.u = f16b(v.x); h.x = c.u; l.x = f16b(v.x - (float)c.h);
  c.u = f16b(v.y); h.y = c.u; l.y = f16b(v.y - (float)c.h);
  c.u = f16b(v.z); h.z = c.u; l.z = f16b(v.z - (float)c.h);
  c.u = f16b(v.w); h.w = c.u; l.w = f16b(v.w - (float)c.h);
  ((ushort4*)hi)[i] = h;
  ((ushort4*)lo)[i] = l;
}

// ---------------------------------------------------------------------------
// Split-fp16 MFMA GEMM: out[m][c] = A[m][:]·(Bh+Bl)[c][:] + bias[c]
// A fp16 single; B fp16 hi/lo. 2 MFMA passes. 128x128 tile, BK=32,
// 256 threads (2x2 waves of 64x64), m97 structure, 3 LDS tiles (24 KB).
// MODE 0: fp32 store. MODE 1: QKV epilogue (RoPE q/k, bf16; v transposed).
// ---------------------------------------------------------------------------
template <int MODE>
__global__ __launch_bounds__(256, 2) void mgemm_k(
    const u16* __restrict__ A, const u16* __restrict__ Bh,
    const u16* __restrict__ Bl, const float* __restrict__ bias,
    float* __restrict__ outF, u16* __restrict__ q, u16* __restrict__ k,
    u16* __restrict__ v, const float2* __restrict__ cs, int K) {
  __shared__ u16 As[128][32];
  __shared__ u16 Bhs[128][32];
  __shared__ u16 Bls[128][32];

  const int t = threadIdx.x;
  const int l = t & 63;
  const int w = t >> 6;
  const int wr = w >> 1, wc = w & 1;
  const int lr = l & 15;
  const int lk = (l >> 4) * 8;
  const int m0 = blockIdx.y * 128, c0 = blockIdx.x * 128;

  const int srow = t >> 2;
  const int skoff = (t & 3) * 8;
  const u16* agA = A + (size_t)(m0 + srow) * K + skoff;
  const u16* agB = Bh + (size_t)(c0 + srow) * K + skoff;
  const u16* agBl = Bl + (size_t)(c0 + srow) * K + skoff;
  const size_t rstep = (size_t)64 * K;
  u16* ldA0 = &As[srow][skoff];
  u16* ldA1 = &As[srow + 64][skoff];
  u16* ldB0 = &Bhs[srow][skoff];
  u16* ldB1 = &Bhs[srow + 64][skoff];
  u16* ldBl0 = &Bls[srow][skoff];
  u16* ldBl1 = &Bls[srow + 64][skoff];

  f32x4 acc[4][4] = {};

  for (int k0 = 0; k0 < K; k0 += 32) {
    __syncthreads();
    gload16(agA + k0, ldA0);
    gload16(agA + rstep + k0, ldA1);
    gload16(agB + k0, ldB0);
    gload16(agB + rstep + k0, ldB1);
    gload16(agBl + k0, ldBl0);
    gload16(agBl + rstep + k0, ldBl1);
    __syncthreads();

    f16x8 bh[4], bl[4];
#pragma unroll
    for (int ni = 0; ni < 4; ni++) {
      bh[ni] = *(const f16x8*)&Bhs[wc * 64 + ni * 16 + lr][lk];
      bl[ni] = *(const f16x8*)&Bls[wc * 64 + ni * 16 + lr][lk];
    }
#pragma unroll
    for (int mi = 0; mi < 4; mi++) {
      f16x8 a = *(const f16x8*)&As[wr * 64 + mi * 16 + lr][lk];
#pragma unroll
      for (int ni = 0; ni < 4; ni++)
        acc[mi][ni] =
            __builtin_amdgcn_mfma_f32_16x16x32_f16(a, bh[ni], acc[mi][ni], 0, 0, 0);
#pragma unroll
      for (int ni = 0; ni < 4; ni++)
        acc[mi][ni] =
            __builtin_amdgcn_mfma_f32_16x16x32_f16(a, bl[ni], acc[mi][ni], 0, 0, 0);
    }
  }

  if (MODE == 0) {
#pragma unroll
    for (int mi = 0; mi < 4; mi++) {
      const int row = m0 + wr * 64 + mi * 16 + (l >> 4) * 4;
#pragma unroll
      for (int ni = 0; ni < 4; ni++) {
        const int col = c0 + wc * 64 + ni * 16 + lr;
        const float bv = bias[col];
#pragma unroll
        for (int r = 0; r < 4; r++)
          outF[(size_t)(row + r) * CDIM + col] = acc[mi][ni][r] + bv;
      }
    }
  } else {
    const int which = c0 >> 10;  // 0=q 1=k 2=v
    u16* dst = which == 0 ? q : (which == 1 ? k : v);
    const bool dorope = which < 2;
    const int h = ((c0 & 1023) + wc * 64) >> 6;
#pragma unroll
    for (int mi = 0; mi < 4; mi++) {
      const int rbase = m0 + wr * 64 + mi * 16 + (l >> 4) * 4;
#pragma unroll
      for (int ni = 0; ni < 4; ni++) {
        const int d = ni * 16 + lr;
        const float bv = bias[c0 + wc * 64 + d];
#pragma unroll
        for (int r = 0; r < 4; r++) {
          const int m = rbase + r;
          const int b = m >> 10, n = m & 1023;
          float y = acc[mi][ni][r] + bv;
          if (dorope) {
            float yp = __shfl_xor(y, 1, 64);
            float2 csv = cs[n * 32 + (d >> 1)];
            y = (l & 1) ? fmaf(yp, csv.y, y * csv.x)
                        : fmaf(-yp, csv.y, y * csv.x);
            dst[(((size_t)b * NH + h) * NSEQ + n) * HD + d] = bf16rne(y);
          } else {
            dst[(((size_t)b * NH + h) * HD + d) * NSEQ + n] = bf16rne(y);
          }
        }
      }
    }
  }
}

// ---------------------------------------------------------------------------
// MFMA flash attention. Block = one (b,h) x 64 q-rows; 4 waves x 16 rows.
// Swizzled K [key][d] / V^T [d][key] tiles via pre-swizzled global source.
// Defer-max (THR=8, wave-uniform vote), lane-local l partials.
// Output o written as fp16 (A-operand of the out GEMM).
// ---------------------------------------------------------------------------
__global__ __launch_bounds__(256) void attn_k(const u16* __restrict__ qg0,
                                              const u16* __restrict__ kg0,
                                              const u16* __restrict__ vtg0,
                                              u16* __restrict__ og) {
  __shared__ __align__(16) u16 Ks[4096];     // 64 keys x 64 d (swizzled)
  __shared__ __align__(16) u16 Vt[4096];     // 64 d x 64 keys (swizzled)
  __shared__ __align__(16) u16 Ps[4][1024];  // per-wave 16 q x 64 keys (swz)
  const int t = threadIdx.x;
  const int l = t & 63, w = t >> 6;
  const int lr = l & 15, lg = l >> 4;
  const int bh = blockIdx.x;
  const int n0 = blockIdx.y * 64;

  // Hoist Q A-fragments (row = w*16+lr, k-chunks c*32+lg*8), scale 1/8.
  bf16x8 qf[2];
  {
    const u16* qp = qg0 + ((size_t)bh * NSEQ + n0 + w * 16 + lr) * HD + lg * 8;
#pragma unroll
    for (int c = 0; c < 2; c++) {
      ushort8 raw = *(const ushort8*)(qp + c * 32);
      bf16x8 o;
#pragma unroll
      for (int j = 0; j < 8; j++) o[j] = (short)bf16rne(bf2f(raw[j]) * 0.125f);
      qf[c] = o;
    }
  }

  const int r0 = t >> 3, b0 = (t & 7) ^ (r0 & 7);
  const int r1 = (256 + t) >> 3, b1 = ((256 + t) & 7) ^ (r1 & 7);
  const u16* kgb = kg0 + (size_t)bh * NSEQ * HD;
  const u16* vgb = vtg0 + (size_t)bh * HD * NSEQ;
  const u16* kga0 = kgb + r0 * 64 + b0 * 8;
  const u16* kga1 = kgb + r1 * 64 + b1 * 8;
  const u16* vga0 = vgb + r0 * 1024 + b0 * 8;
  const u16* vga1 = vgb + r1 * 1024 + b1 * 8;
  u16* ksd0 = Ks + (size_t)t * 8;
  u16* ksd1 = Ks + (size_t)(256 + t) * 8;
  u16* vtd0 = Vt + (size_t)t * 8;
  u16* vtd1 = Vt + (size_t)(256 + t) * 8;

  float m_run[4], l_run[4];
  f32x4 oa[4] = {};
#pragma unroll
  for (int r = 0; r < 4; r++) { m_run[r] = -INFINITY; l_run[r] = 0.f; }

  for (int kt = 0; kt < 16; kt++) {
    __syncthreads();  // prior tile's LDS reads complete
    gload16(kga0 + kt * 4096, ksd0);
    gload16(kga1 + kt * 4096, ksd1);
    gload16(vga0 + kt * 64, vtd0);
    gload16(vga1 + kt * 64, vtd1);
    __syncthreads();  // staging drained

    // S = Q K^T
    f32x4 s[4] = {};
#pragma unroll
    for (int c = 0; c < 2; c++) {
#pragma unroll
      for (int ni = 0; ni < 4; ni++) {
        const int kr = ni * 16 + lr;
        bf16x8 kf = *(const bf16x8*)&Ks[kr * 64 + (((c * 4 + lg) ^ (kr & 7)) * 8)];
        s[ni] = __builtin_amdgcn_mfma_f32_16x16x32_bf16(qf[c], kf, s[ni], 0, 0, 0);
      }
    }

    // Row maxima (shfl over the 16 col-lanes)
    float tm[4];
#pragma unroll
    for (int r = 0; r < 4; r++) {
      float m1 = fmaxf(fmaxf(s[0][r], s[1][r]), fmaxf(s[2][r], s[3][r]));
      m1 = fmaxf(m1, __shfl_xor(m1, 1, 64));
      m1 = fmaxf(m1, __shfl_xor(m1, 2, 64));
      m1 = fmaxf(m1, __shfl_xor(m1, 4, 64));
      m1 = fmaxf(m1, __shfl_xor(m1, 8, 64));
      tm[r] = m1;
    }
    // Defer-max: rescale only if some row grew past THR=8 (wave-uniform)
    const bool ok = (tm[0] <= m_run[0] + 8.f) && (tm[1] <= m_run[1] + 8.f) &&
                    (tm[2] <= m_run[2] + 8.f) && (tm[3] <= m_run[3] + 8.f);
    if (!__all(ok)) {
#pragma unroll
      for (int r = 0; r < 4; r++) {
        const float mn = fmaxf(m_run[r], tm[r]);
        const float fs = __expf(m_run[r] - mn);
        m_run[r] = mn;
        l_run[r] *= fs;
#pragma unroll
        for (int ni = 0; ni < 4; ni++) oa[ni][r] *= fs;
      }
    }
    // P = exp(S - m); lane-local l partials; store P (swizzled, own wave)
#pragma unroll
    for (int r = 0; r < 4; r++) {
      float p[4], ps = 0.f;
#pragma unroll
      for (int ni = 0; ni < 4; ni++) { p[ni] = __expf(s[ni][r] - m_run[r]); ps += p[ni]; }
      l_run[r] += ps;
      const int prow = lg * 4 + r;
      const int sw = prow & 7;
#pragma unroll
      for (int ni = 0; ni < 4; ni++)
        Ps[w][prow * 64 + (((ni * 2 + (lr >> 3)) ^ sw) * 8) + (lr & 7)] =
            bf16rne(p[ni]);
    }
    // No barrier: Ps is read only by the writing wave (same-wave DS in-order)

    // O += P V
#pragma unroll
    for (int c = 0; c < 2; c++) {
      bf16x8 pa = *(const bf16x8*)&Ps[w][lr * 64 + (((c * 4 + lg) ^ (lr & 7)) * 8)];
#pragma unroll
      for (int ni = 0; ni < 4; ni++) {
        const int dr = ni * 16 + lr;
        bf16x8 vf = *(const bf16x8*)&Vt[dr * 64 + (((c * 4 + lg) ^ (dr & 7)) * 8)];
        oa[ni] = __builtin_amdgcn_mfma_f32_16x16x32_bf16(pa, vf, oa[ni], 0, 0, 0);
      }
    }
  }

  const int b = bh >> 4, h = bh & 15;
#pragma unroll
  for (int r = 0; r < 4; r++) {
    float lv = l_run[r];
    lv += __shfl_xor(lv, 1, 64);
    lv += __shfl_xor(lv, 2, 64);
    lv += __shfl_xor(lv, 4, 64);
    lv += __shfl_xor(lv, 8, 64);
    const float inv = 1.0f / lv;
    const size_t n = n0 + w * 16 + lg * 4 + r;
    const size_t base = ((size_t)b * NSEQ + n) * CDIM + h * HD;
#pragma unroll
    for (int ni = 0; ni < 4; ni++)
      og[base + ni * 16 + lr] = f16b(oa[ni][r] * inv);
  }
}

// ---------------------------------------------------------------------------
extern "C" void kernel_launch(void* const* d_in, const int* in_sizes, int n_in,
                              void* d_out, int out_size, void* d_ws, size_t ws_size,
                              hipStream_t stream) {
  const float* x      = (const float*)d_in[0];
  const float* wqkv_w = (const float*)d_in[1];
  const float* wqkv_b = (const float*)d_in[2];
  const float* out_w  = (const float*)d_in[3];
  const float* out_b  = (const float*)d_in[4];
  float* out = (float*)d_out;
  u16* ws = (u16*)d_ws;
  float2* cs = (float2*)((char*)d_ws + CS_B);

  rope_table_k<<<dim3((NSEQ * 32 + 255) / 256), 256, 0, stream>>>(cs);
  cvt16_k<<<dim3(8192), 256, 0, stream>>>(x, ws + XH_U, 2097152);
  splitw_k<<<dim3(3072), 256, 0, stream>>>(wqkv_w, ws + WQH_U, ws + WQL_U, 786432);
  splitw_k<<<dim3(1024), 256, 0, stream>>>(out_w, ws + OWH_U, ws + OWL_U, 262144);

  // QKV GEMM (A=x fp16, B=wqkv hi/lo) + bias + RoPE + bf16 scatter (v^T)
  mgemm_k<1><<<dim3(TC / 128, (NB * NSEQ) / 128), 256, 0, stream>>>(
      ws + XH_U, ws + WQH_U, ws + WQL_U, wqkv_b, nullptr,
      ws + Q_U, ws + K_U, ws + V_U, cs, CDIM);

  // flash attention -> o fp16 (overwrites x region)
  attn_k<<<dim3(NB * NH, NSEQ / 64), 256, 0, stream>>>(
      ws + Q_U, ws + K_U, ws + V_U, ws + XH_U);

  // out GEMM (A=o fp16, B=out_w hi/lo) + bias -> fp32 d_out
  mgemm_k<0><<<dim3(CDIM / 128, (NB * NSEQ) / 128), 256, 0, stream>>>(
      ws + XH_U, ws + OWH_U, ws + OWL_U, out_b, out,
      nullptr, nullptr, nullptr, cs, CDIM);
}

// Round 5
// 257.866 us; speedup vs baseline: 6.9628x; 1.2099x over previous
//
#include <hip/hip_runtime.h>
#include <math.h>

// Problem constants
#define NB   8
#define NSEQ 1024
#define CDIM 1024
#define NH   16
#define HD   64
#define TC   3072

typedef unsigned short u16;
typedef __attribute__((ext_vector_type(8))) _Float16 f16x8;
typedef __attribute__((ext_vector_type(8))) unsigned short ushort8;
typedef __attribute__((ext_vector_type(4))) float f32x4;

// Workspace layout in u16 units (all fp16):
//   q,k : [B][H][N][D] ; vT : [B][H][D][N]
//   xh  : [8192][1024] (x; later overwritten by o)
//   wqh : [3072][1024] ; owh : [1024][1024]
//   cs  : float2[1024][32] RoPE table (byte offset CS_B)
#define Q_U   ((size_t)0)
#define K_U   ((size_t)8388608)
#define V_U   ((size_t)16777216)
#define XH_U  ((size_t)25165824)
#define WQH_U ((size_t)33554432)
#define OWH_U ((size_t)36700160)
#define CS_B  ((size_t)100663296)

__device__ inline u16 f16b(float f) {
  union { _Float16 h; u16 u; } c;
  c.h = (_Float16)f;
  return c.u;
}
__device__ inline void gload16(const u16* g, u16* l) {
  __builtin_amdgcn_global_load_lds(
      (const __attribute__((address_space(1))) void*)g,
      (__attribute__((address_space(3))) void*)l, 16, 0, 0);
}

// ---------------------------------------------------------------------------
__global__ __launch_bounds__(256) void rope_table_k(float2* __restrict__ cs) {
  int idx = blockIdx.x * 256 + threadIdx.x;
  if (idx >= NSEQ * 32) return;
  int n = idx >> 5, p = idx & 31;
  int t = p >> 1;
  int pos = (p & 1) ? (n & 31) : (n >> 5);
  float th = (float)pow(10000.0, -(double)t / 16.0);
  float ang = (float)pos * th;
  cs[idx] = make_float2(cosf(ang), sinf(ang));
}

// ---------------------------------------------------------------------------
// fp32 -> fp16 convert (RNE), float4-vectorized
__global__ __launch_bounds__(256) void cvt16_k(const float* __restrict__ in,
                                               u16* __restrict__ hi, int n4) {
  int i = blockIdx.x * 256 + threadIdx.x;
  if (i >= n4) return;
  float4 v = ((const float4*)in)[i];
  ushort4 h;
  h.x = f16b(v.x); h.y = f16b(v.y); h.z = f16b(v.z); h.w = f16b(v.w);
  ((ushort4*)hi)[i] = h;
}

// ---------------------------------------------------------------------------
// fp16 MFMA GEMM (exact m97 geometry): out[m][c] = A[m][:]·B[c][:] + bias[c]
// 128x128 tile, BK=32, 256 threads (2x2 waves of 64x64), 2 LDS tiles (16 KB),
// 4 global_load_lds + 16 MFMA per K-step.
// MODE 0: fp32 store. MODE 1: QKV epilogue (RoPE q/k, fp16; v transposed).
// ---------------------------------------------------------------------------
template <int MODE>
__global__ __launch_bounds__(256, 2) void mgemm_k(
    const u16* __restrict__ A, const u16* __restrict__ B,
    const float* __restrict__ bias, float* __restrict__ outF,
    u16* __restrict__ q, u16* __restrict__ k, u16* __restrict__ v,
    const float2* __restrict__ cs, int K) {
  __shared__ u16 As[128][32];
  __shared__ u16 Bs[128][32];

  const int t = threadIdx.x;
  const int l = t & 63;
  const int w = t >> 6;
  const int wr = w >> 1, wc = w & 1;
  const int lr = l & 15;
  const int lk = (l >> 4) * 8;
  const int m0 = blockIdx.y * 128, c0 = blockIdx.x * 128;

  const int srow = t >> 2;
  const int skoff = (t & 3) * 8;
  const u16* agA = A + (size_t)(m0 + srow) * K + skoff;
  const u16* agB = B + (size_t)(c0 + srow) * K + skoff;
  const size_t rstep = (size_t)64 * K;
  u16* ldA0 = &As[srow][skoff];
  u16* ldA1 = &As[srow + 64][skoff];
  u16* ldB0 = &Bs[srow][skoff];
  u16* ldB1 = &Bs[srow + 64][skoff];

  f32x4 acc[4][4] = {};

  for (int k0 = 0; k0 < K; k0 += 32) {
    __syncthreads();
    gload16(agA + k0, ldA0);
    gload16(agA + rstep + k0, ldA1);
    gload16(agB + k0, ldB0);
    gload16(agB + rstep + k0, ldB1);
    __syncthreads();

    f16x8 bfr[4];
#pragma unroll
    for (int ni = 0; ni < 4; ni++)
      bfr[ni] = *(const f16x8*)&Bs[wc * 64 + ni * 16 + lr][lk];
#pragma unroll
    for (int mi = 0; mi < 4; mi++) {
      f16x8 a = *(const f16x8*)&As[wr * 64 + mi * 16 + lr][lk];
#pragma unroll
      for (int ni = 0; ni < 4; ni++)
        acc[mi][ni] =
            __builtin_amdgcn_mfma_f32_16x16x32_f16(a, bfr[ni], acc[mi][ni], 0, 0, 0);
    }
  }

  if (MODE == 0) {
#pragma unroll
    for (int mi = 0; mi < 4; mi++) {
      const int row = m0 + wr * 64 + mi * 16 + (l >> 4) * 4;
#pragma unroll
      for (int ni = 0; ni < 4; ni++) {
        const int col = c0 + wc * 64 + ni * 16 + lr;
        const float bv = bias[col];
#pragma unroll
        for (int r = 0; r < 4; r++)
          outF[(size_t)(row + r) * CDIM + col] = acc[mi][ni][r] + bv;
      }
    }
  } else {
    const int which = c0 >> 10;  // 0=q 1=k 2=v
    u16* dst = which == 0 ? q : (which == 1 ? k : v);
    const bool dorope = which < 2;
    const int h = ((c0 & 1023) + wc * 64) >> 6;
#pragma unroll
    for (int mi = 0; mi < 4; mi++) {
      const int rbase = m0 + wr * 64 + mi * 16 + (l >> 4) * 4;
#pragma unroll
      for (int ni = 0; ni < 4; ni++) {
        const int d = ni * 16 + lr;
        const float bv = bias[c0 + wc * 64 + d];
#pragma unroll
        for (int r = 0; r < 4; r++) {
          const int m = rbase + r;
          const int b = m >> 10, n = m & 1023;
          float y = acc[mi][ni][r] + bv;
          if (dorope) {
            float yp = __shfl_xor(y, 1, 64);
            float2 csv = cs[n * 32 + (d >> 1)];
            y = (l & 1) ? fmaf(yp, csv.y, y * csv.x)
                        : fmaf(-yp, csv.y, y * csv.x);
            dst[(((size_t)b * NH + h) * NSEQ + n) * HD + d] = f16b(y);
          } else {
            // v: transposed store [bh][d][n]
            dst[(((size_t)b * NH + h) * HD + d) * NSEQ + n] = f16b(y);
          }
        }
      }
    }
  }
}

// ---------------------------------------------------------------------------
// MFMA flash attention, all-fp16 operands. Block = one (b,h) x 64 q-rows;
// 4 waves x 16 rows. Swizzled K [key][d] / V^T [d][key] via pre-swizzled
// global source. Defer-max (THR=8), lane-local l partials, per-wave P (f16).
// ---------------------------------------------------------------------------
__global__ __launch_bounds__(256) void attn_k(const u16* __restrict__ qg0,
                                              const u16* __restrict__ kg0,
                                              const u16* __restrict__ vtg0,
                                              u16* __restrict__ og) {
  __shared__ __align__(16) u16 Ks[4096];     // 64 keys x 64 d (swizzled)
  __shared__ __align__(16) u16 Vt[4096];     // 64 d x 64 keys (swizzled)
  __shared__ __align__(16) u16 Ps[4][1024];  // per-wave 16 q x 64 keys (swz)
  const int t = threadIdx.x;
  const int l = t & 63, w = t >> 6;
  const int lr = l & 15, lg = l >> 4;
  const int bh = blockIdx.x;
  const int n0 = blockIdx.y * 64;

  // Hoist Q A-fragments (row = w*16+lr, k-chunks c*32+lg*8), scale 1/8 (exact)
  f16x8 qf[2];
  {
    const u16* qp = qg0 + ((size_t)bh * NSEQ + n0 + w * 16 + lr) * HD + lg * 8;
#pragma unroll
    for (int c = 0; c < 2; c++) {
      f16x8 raw = *(const f16x8*)(qp + c * 32);
#pragma unroll
      for (int j = 0; j < 8; j++) raw[j] = raw[j] * (_Float16)0.125f;
      qf[c] = raw;
    }
  }

  const int r0 = t >> 3, b0 = (t & 7) ^ (r0 & 7);
  const int r1 = (256 + t) >> 3, b1 = ((256 + t) & 7) ^ (r1 & 7);
  const u16* kgb = kg0 + (size_t)bh * NSEQ * HD;
  const u16* vgb = vtg0 + (size_t)bh * HD * NSEQ;
  const u16* kga0 = kgb + r0 * 64 + b0 * 8;
  const u16* kga1 = kgb + r1 * 64 + b1 * 8;
  const u16* vga0 = vgb + r0 * 1024 + b0 * 8;
  const u16* vga1 = vgb + r1 * 1024 + b1 * 8;
  u16* ksd0 = Ks + (size_t)t * 8;
  u16* ksd1 = Ks + (size_t)(256 + t) * 8;
  u16* vtd0 = Vt + (size_t)t * 8;
  u16* vtd1 = Vt + (size_t)(256 + t) * 8;

  float m_run[4], l_run[4];
  f32x4 oa[4] = {};
#pragma unroll
  for (int r = 0; r < 4; r++) { m_run[r] = -INFINITY; l_run[r] = 0.f; }

  for (int kt = 0; kt < 16; kt++) {
    __syncthreads();  // prior tile's LDS reads complete
    gload16(kga0 + kt * 4096, ksd0);
    gload16(kga1 + kt * 4096, ksd1);
    gload16(vga0 + kt * 64, vtd0);
    gload16(vga1 + kt * 64, vtd1);
    __syncthreads();  // staging drained

    // S = Q K^T
    f32x4 s[4] = {};
#pragma unroll
    for (int c = 0; c < 2; c++) {
#pragma unroll
      for (int ni = 0; ni < 4; ni++) {
        const int kr = ni * 16 + lr;
        f16x8 kf = *(const f16x8*)&Ks[kr * 64 + (((c * 4 + lg) ^ (kr & 7)) * 8)];
        s[ni] = __builtin_amdgcn_mfma_f32_16x16x32_f16(qf[c], kf, s[ni], 0, 0, 0);
      }
    }

    // Row maxima (shfl over the 16 col-lanes)
    float tm[4];
#pragma unroll
    for (int r = 0; r < 4; r++) {
      float m1 = fmaxf(fmaxf(s[0][r], s[1][r]), fmaxf(s[2][r], s[3][r]));
      m1 = fmaxf(m1, __shfl_xor(m1, 1, 64));
      m1 = fmaxf(m1, __shfl_xor(m1, 2, 64));
      m1 = fmaxf(m1, __shfl_xor(m1, 4, 64));
      m1 = fmaxf(m1, __shfl_xor(m1, 8, 64));
      tm[r] = m1;
    }
    // Defer-max: rescale only if some row grew past THR=8 (wave-uniform)
    const bool ok = (tm[0] <= m_run[0] + 8.f) && (tm[1] <= m_run[1] + 8.f) &&
                    (tm[2] <= m_run[2] + 8.f) && (tm[3] <= m_run[3] + 8.f);
    if (!__all(ok)) {
#pragma unroll
      for (int r = 0; r < 4; r++) {
        const float mn = fmaxf(m_run[r], tm[r]);
        const float fs = __expf(m_run[r] - mn);
        m_run[r] = mn;
        l_run[r] *= fs;
#pragma unroll
        for (int ni = 0; ni < 4; ni++) oa[ni][r] *= fs;
      }
    }
    // P = exp(S - m) (<= e^8); lane-local l partials; store P fp16 (own wave)
#pragma unroll
    for (int r = 0; r < 4; r++) {
      float p[4], ps = 0.f;
#pragma unroll
      for (int ni = 0; ni < 4; ni++) { p[ni] = __expf(s[ni][r] - m_run[r]); ps += p[ni]; }
      l_run[r] += ps;
      const int prow = lg * 4 + r;
      const int sw = prow & 7;
#pragma unroll
      for (int ni = 0; ni < 4; ni++)
        Ps[w][prow * 64 + (((ni * 2 + (lr >> 3)) ^ sw) * 8) + (lr & 7)] =
            f16b(p[ni]);
    }
    // No barrier: Ps is read only by the writing wave (same-wave DS in-order)

    // O += P V
#pragma unroll
    for (int c = 0; c < 2; c++) {
      f16x8 pa = *(const f16x8*)&Ps[w][lr * 64 + (((c * 4 + lg) ^ (lr & 7)) * 8)];
#pragma unroll
      for (int ni = 0; ni < 4; ni++) {
        const int dr = ni * 16 + lr;
        f16x8 vf = *(const f16x8*)&Vt[dr * 64 + (((c * 4 + lg) ^ (dr & 7)) * 8)];
        oa[ni] = __builtin_amdgcn_mfma_f32_16x16x32_f16(pa, vf, oa[ni], 0, 0, 0);
      }
    }
  }

  const int b = bh >> 4, h = bh & 15;
#pragma unroll
  for (int r = 0; r < 4; r++) {
    float lv = l_run[r];
    lv += __shfl_xor(lv, 1, 64);
    lv += __shfl_xor(lv, 2, 64);
    lv += __shfl_xor(lv, 4, 64);
    lv += __shfl_xor(lv, 8, 64);
    const float inv = 1.0f / lv;
    const size_t n = n0 + w * 16 + lg * 4 + r;
    const size_t base = ((size_t)b * NSEQ + n) * CDIM + h * HD;
#pragma unroll
    for (int ni = 0; ni < 4; ni++)
      og[base + ni * 16 + lr] = f16b(oa[ni][r] * inv);
  }
}

// ---------------------------------------------------------------------------
extern "C" void kernel_launch(void* const* d_in, const int* in_sizes, int n_in,
                              void* d_out, int out_size, void* d_ws, size_t ws_size,
                              hipStream_t stream) {
  const float* x      = (const float*)d_in[0];
  const float* wqkv_w = (const float*)d_in[1];
  const float* wqkv_b = (const float*)d_in[2];
  const float* out_w  = (const float*)d_in[3];
  const float* out_b  = (const float*)d_in[4];
  float* out = (float*)d_out;
  u16* ws = (u16*)d_ws;
  float2* cs = (float2*)((char*)d_ws + CS_B);

  rope_table_k<<<dim3((NSEQ * 32 + 255) / 256), 256, 0, stream>>>(cs);
  cvt16_k<<<dim3(8192), 256, 0, stream>>>(x, ws + XH_U, 2097152);
  cvt16_k<<<dim3(3072), 256, 0, stream>>>(wqkv_w, ws + WQH_U, 786432);
  cvt16_k<<<dim3(1024), 256, 0, stream>>>(out_w, ws + OWH_U, 262144);

  // QKV GEMM (fp16 1-pass) + bias + RoPE + fp16 scatter (v^T)
  mgemm_k<1><<<dim3(TC / 128, (NB * NSEQ) / 128), 256, 0, stream>>>(
      ws + XH_U, ws + WQH_U, wqkv_b, nullptr,
      ws + Q_U, ws + K_U, ws + V_U, cs, CDIM);

  // flash attention (fp16 MFMA) -> o fp16 (overwrites x region)
  attn_k<<<dim3(NB * NH, NSEQ / 64), 256, 0, stream>>>(
      ws + Q_U, ws + K_U, ws + V_U, ws + XH_U);

  // out GEMM (fp16 1-pass) + bias -> fp32 d_out
  mgemm_k<0><<<dim3(CDIM / 128, (NB * NSEQ) / 128), 256, 0, stream>>>(
      ws + XH_U, ws + OWH_U, out_b, out,
      nullptr, nullptr, nullptr, cs, CDIM);
}

// Round 6
// 251.911 us; speedup vs baseline: 7.1273x; 1.0236x over previous
//
#include <hip/hip_runtime.h>
#include <math.h>

// Problem constants
#define NB   8
#define NSEQ 1024
#define CDIM 1024
#define NH   16
#define HD   64
#define TC   3072

typedef unsigned short u16;
typedef __attribute__((ext_vector_type(8))) _Float16 f16x8;
typedef __attribute__((ext_vector_type(8))) unsigned short ushort8;
typedef __attribute__((ext_vector_type(4))) float f32x4;

// Workspace layout in u16 units (all fp16):
//   q,k : [B][H][N][D] ; vT : [B][H][D][N]
//   xh  : [8192][1024] (x; later overwritten by o)
//   wqh : [3072][1024] ; owh : [1024][1024]
//   cs  : float2[1024][32] RoPE table (byte offset CS_B)
#define Q_U   ((size_t)0)
#define K_U   ((size_t)8388608)
#define V_U   ((size_t)16777216)
#define XH_U  ((size_t)25165824)
#define WQH_U ((size_t)33554432)
#define OWH_U ((size_t)36700160)
#define CS_B  ((size_t)100663296)

__device__ inline u16 f16b(float f) {
  union { _Float16 h; u16 u; } c;
  c.h = (_Float16)f;
  return c.u;
}
__device__ inline void gload16(const u16* g, u16* l) {
  __builtin_amdgcn_global_load_lds(
      (const __attribute__((address_space(1))) void*)g,
      (__attribute__((address_space(3))) void*)l, 16, 0, 0);
}

// ---------------------------------------------------------------------------
__global__ __launch_bounds__(256) void rope_table_k(float2* __restrict__ cs) {
  int idx = blockIdx.x * 256 + threadIdx.x;
  if (idx >= NSEQ * 32) return;
  int n = idx >> 5, p = idx & 31;
  int t = p >> 1;
  int pos = (p & 1) ? (n & 31) : (n >> 5);
  float th = (float)pow(10000.0, -(double)t / 16.0);
  float ang = (float)pos * th;
  cs[idx] = make_float2(cosf(ang), sinf(ang));
}

// ---------------------------------------------------------------------------
// fp32 -> fp16 convert (RNE), float4-vectorized
__global__ __launch_bounds__(256) void cvt16_k(const float* __restrict__ in,
                                               u16* __restrict__ hi, int n4) {
  int i = blockIdx.x * 256 + threadIdx.x;
  if (i >= n4) return;
  float4 v = ((const float4*)in)[i];
  ushort4 h;
  h.x = f16b(v.x); h.y = f16b(v.y); h.z = f16b(v.z); h.w = f16b(v.w);
  ((ushort4*)hi)[i] = h;
}

// ---------------------------------------------------------------------------
// fp16 MFMA GEMM, double-buffered LDS + stage-ahead (T3 minimum 2-phase):
//   out[m][c] = A[m][:]·B[c][:] + bias[c]
// 128x128 tile, BK=32, 256 threads (2x2 waves of 64x64), LDS 32 KB.
// Per K-step: issue next tile's 4 global_load_lds, then ds_read+16 MFMA of
// current tile, then ONE __syncthreads (implicit vmcnt(0) drain covers the
// prefetch, whose latency hid under this step's compute).
// XCD-chunked bijective swizzle: each XCD gets a contiguous cx-major region
// so its 24-column sweep reuses the same A row-panel from its own L2.
// MODE 0: fp32 store. MODE 1: QKV epilogue (RoPE q/k, fp16; v transposed).
// ---------------------------------------------------------------------------
template <int MODE>
__global__ __launch_bounds__(256, 2) void mgemm_k(
    const u16* __restrict__ A, const u16* __restrict__ B,
    const float* __restrict__ bias, float* __restrict__ outF,
    u16* __restrict__ q, u16* __restrict__ k, u16* __restrict__ v,
    const float2* __restrict__ cs, int K) {
  __shared__ u16 As[2][128][32];
  __shared__ u16 Bs[2][128][32];

  // XCD-aware bijective swizzle (nwg % 8 == 0 for both call sites)
  const int nwg = gridDim.x * gridDim.y;
  const int bid = blockIdx.y * gridDim.x + blockIdx.x;
  const int swz = (bid & 7) * (nwg >> 3) + (bid >> 3);
  const int bx = swz % gridDim.x;
  const int by = swz / gridDim.x;

  const int t = threadIdx.x;
  const int l = t & 63;
  const int w = t >> 6;
  const int wr = w >> 1, wc = w & 1;
  const int lr = l & 15;
  const int lk = (l >> 4) * 8;
  const int m0 = by * 128, c0 = bx * 128;

  const int srow = t >> 2;
  const int skoff = (t & 3) * 8;
  const int soff = srow * 32 + skoff;  // u16 offset inside one 128x32 buffer
  const u16* agA = A + (size_t)(m0 + srow) * K + skoff;
  const u16* agB = B + (size_t)(c0 + srow) * K + skoff;
  const size_t rstep = (size_t)64 * K;
  u16* baseA = &As[0][0][0];
  u16* baseB = &Bs[0][0][0];

  f32x4 acc[4][4] = {};

  const int NT = K >> 5;  // 32 K-steps
  // prologue: stage tile 0 into buf 0
  {
    u16* dA = baseA + soff;
    u16* dB = baseB + soff;
    gload16(agA, dA);
    gload16(agA + rstep, dA + 64 * 32);
    gload16(agB, dB);
    gload16(agB + rstep, dB + 64 * 32);
  }
  __syncthreads();

  int cur = 0;
  for (int kt = 0; kt < NT; ++kt) {
    // stage next tile into the other buffer (its previous readers finished
    // at the barrier ending step kt-1)
    if (kt + 1 < NT) {
      const int koff = (kt + 1) << 5;
      u16* dA = baseA + ((cur ^ 1) * 4096) + soff;
      u16* dB = baseB + ((cur ^ 1) * 4096) + soff;
      gload16(agA + koff, dA);
      gload16(agA + rstep + koff, dA + 64 * 32);
      gload16(agB + koff, dB);
      gload16(agB + rstep + koff, dB + 64 * 32);
    }
    // compute current tile
    const u16* cA = baseA + cur * 4096;
    const u16* cB = baseB + cur * 4096;
    f16x8 bfr[4];
#pragma unroll
    for (int ni = 0; ni < 4; ni++)
      bfr[ni] = *(const f16x8*)(cB + (wc * 64 + ni * 16 + lr) * 32 + lk);
#pragma unroll
    for (int mi = 0; mi < 4; mi++) {
      f16x8 a = *(const f16x8*)(cA + (wr * 64 + mi * 16 + lr) * 32 + lk);
#pragma unroll
      for (int ni = 0; ni < 4; ni++)
        acc[mi][ni] =
            __builtin_amdgcn_mfma_f32_16x16x32_f16(a, bfr[ni], acc[mi][ni], 0, 0, 0);
    }
    __syncthreads();  // drains vmcnt(0): next tile ready; LDS reads done
    cur ^= 1;
  }

  if (MODE == 0) {
#pragma unroll
    for (int mi = 0; mi < 4; mi++) {
      const int row = m0 + wr * 64 + mi * 16 + (l >> 4) * 4;
#pragma unroll
      for (int ni = 0; ni < 4; ni++) {
        const int col = c0 + wc * 64 + ni * 16 + lr;
        const float bv = bias[col];
#pragma unroll
        for (int r = 0; r < 4; r++)
          outF[(size_t)(row + r) * CDIM + col] = acc[mi][ni][r] + bv;
      }
    }
  } else {
    const int which = c0 >> 10;  // 0=q 1=k 2=v
    u16* dst = which == 0 ? q : (which == 1 ? k : v);
    const bool dorope = which < 2;
    const int h = ((c0 & 1023) + wc * 64) >> 6;
#pragma unroll
    for (int mi = 0; mi < 4; mi++) {
      const int rbase = m0 + wr * 64 + mi * 16 + (l >> 4) * 4;
#pragma unroll
      for (int ni = 0; ni < 4; ni++) {
        const int d = ni * 16 + lr;
        const float bv = bias[c0 + wc * 64 + d];
#pragma unroll
        for (int r = 0; r < 4; r++) {
          const int m = rbase + r;
          const int b = m >> 10, n = m & 1023;
          float y = acc[mi][ni][r] + bv;
          if (dorope) {
            float yp = __shfl_xor(y, 1, 64);
            float2 csv = cs[n * 32 + (d >> 1)];
            y = (l & 1) ? fmaf(yp, csv.y, y * csv.x)
                        : fmaf(-yp, csv.y, y * csv.x);
            dst[(((size_t)b * NH + h) * NSEQ + n) * HD + d] = f16b(y);
          } else {
            // v: transposed store [bh][d][n]
            dst[(((size_t)b * NH + h) * HD + d) * NSEQ + n] = f16b(y);
          }
        }
      }
    }
  }
}

// ---------------------------------------------------------------------------
// MFMA flash attention, all-fp16 operands. Block = one (b,h) x 64 q-rows;
// 4 waves x 16 rows. Swizzled K [key][d] / V^T [d][key] via pre-swizzled
// global source. Defer-max (THR=8), lane-local l partials, per-wave P (f16).
// ---------------------------------------------------------------------------
__global__ __launch_bounds__(256) void attn_k(const u16* __restrict__ qg0,
                                              const u16* __restrict__ kg0,
                                              const u16* __restrict__ vtg0,
                                              u16* __restrict__ og) {
  __shared__ __align__(16) u16 Ks[4096];     // 64 keys x 64 d (swizzled)
  __shared__ __align__(16) u16 Vt[4096];     // 64 d x 64 keys (swizzled)
  __shared__ __align__(16) u16 Ps[4][1024];  // per-wave 16 q x 64 keys (swz)
  const int t = threadIdx.x;
  const int l = t & 63, w = t >> 6;
  const int lr = l & 15, lg = l >> 4;
  const int bh = blockIdx.x;
  const int n0 = blockIdx.y * 64;

  // Hoist Q A-fragments (row = w*16+lr, k-chunks c*32+lg*8), scale 1/8 (exact)
  f16x8 qf[2];
  {
    const u16* qp = qg0 + ((size_t)bh * NSEQ + n0 + w * 16 + lr) * HD + lg * 8;
#pragma unroll
    for (int c = 0; c < 2; c++) {
      f16x8 raw = *(const f16x8*)(qp + c * 32);
#pragma unroll
      for (int j = 0; j < 8; j++) raw[j] = raw[j] * (_Float16)0.125f;
      qf[c] = raw;
    }
  }

  const int r0 = t >> 3, b0 = (t & 7) ^ (r0 & 7);
  const int r1 = (256 + t) >> 3, b1 = ((256 + t) & 7) ^ (r1 & 7);
  const u16* kgb = kg0 + (size_t)bh * NSEQ * HD;
  const u16* vgb = vtg0 + (size_t)bh * HD * NSEQ;
  const u16* kga0 = kgb + r0 * 64 + b0 * 8;
  const u16* kga1 = kgb + r1 * 64 + b1 * 8;
  const u16* vga0 = vgb + r0 * 1024 + b0 * 8;
  const u16* vga1 = vgb + r1 * 1024 + b1 * 8;
  u16* ksd0 = Ks + (size_t)t * 8;
  u16* ksd1 = Ks + (size_t)(256 + t) * 8;
  u16* vtd0 = Vt + (size_t)t * 8;
  u16* vtd1 = Vt + (size_t)(256 + t) * 8;

  float m_run[4], l_run[4];
  f32x4 oa[4] = {};
#pragma unroll
  for (int r = 0; r < 4; r++) { m_run[r] = -INFINITY; l_run[r] = 0.f; }

  for (int kt = 0; kt < 16; kt++) {
    __syncthreads();  // prior tile's LDS reads complete
    gload16(kga0 + kt * 4096, ksd0);
    gload16(kga1 + kt * 4096, ksd1);
    gload16(vga0 + kt * 64, vtd0);
    gload16(vga1 + kt * 64, vtd1);
    __syncthreads();  // staging drained

    // S = Q K^T
    f32x4 s[4] = {};
#pragma unroll
    for (int c = 0; c < 2; c++) {
#pragma unroll
      for (int ni = 0; ni < 4; ni++) {
        const int kr = ni * 16 + lr;
        f16x8 kf = *(const f16x8*)&Ks[kr * 64 + (((c * 4 + lg) ^ (kr & 7)) * 8)];
        s[ni] = __builtin_amdgcn_mfma_f32_16x16x32_f16(qf[c], kf, s[ni], 0, 0, 0);
      }
    }

    // Row maxima (shfl over the 16 col-lanes)
    float tm[4];
#pragma unroll
    for (int r = 0; r < 4; r++) {
      float m1 = fmaxf(fmaxf(s[0][r], s[1][r]), fmaxf(s[2][r], s[3][r]));
      m1 = fmaxf(m1, __shfl_xor(m1, 1, 64));
      m1 = fmaxf(m1, __shfl_xor(m1, 2, 64));
      m1 = fmaxf(m1, __shfl_xor(m1, 4, 64));
      m1 = fmaxf(m1, __shfl_xor(m1, 8, 64));
      tm[r] = m1;
    }
    // Defer-max: rescale only if some row grew past THR=8 (wave-uniform)
    const bool ok = (tm[0] <= m_run[0] + 8.f) && (tm[1] <= m_run[1] + 8.f) &&
                    (tm[2] <= m_run[2] + 8.f) && (tm[3] <= m_run[3] + 8.f);
    if (!__all(ok)) {
#pragma unroll
      for (int r = 0; r < 4; r++) {
        const float mn = fmaxf(m_run[r], tm[r]);
        const float fs = __expf(m_run[r] - mn);
        m_run[r] = mn;
        l_run[r] *= fs;
#pragma unroll
        for (int ni = 0; ni < 4; ni++) oa[ni][r] *= fs;
      }
    }
    // P = exp(S - m) (<= e^8); lane-local l partials; store P fp16 (own wave)
#pragma unroll
    for (int r = 0; r < 4; r++) {
      float p[4], ps = 0.f;
#pragma unroll
      for (int ni = 0; ni < 4; ni++) { p[ni] = __expf(s[ni][r] - m_run[r]); ps += p[ni]; }
      l_run[r] += ps;
      const int prow = lg * 4 + r;
      const int sw = prow & 7;
#pragma unroll
      for (int ni = 0; ni < 4; ni++)
        Ps[w][prow * 64 + (((ni * 2 + (lr >> 3)) ^ sw) * 8) + (lr & 7)] =
            f16b(p[ni]);
    }
    // No barrier: Ps is read only by the writing wave (same-wave DS in-order)

    // O += P V
#pragma unroll
    for (int c = 0; c < 2; c++) {
      f16x8 pa = *(const f16x8*)&Ps[w][lr * 64 + (((c * 4 + lg) ^ (lr & 7)) * 8)];
#pragma unroll
      for (int ni = 0; ni < 4; ni++) {
        const int dr = ni * 16 + lr;
        f16x8 vf = *(const f16x8*)&Vt[dr * 64 + (((c * 4 + lg) ^ (dr & 7)) * 8)];
        oa[ni] = __builtin_amdgcn_mfma_f32_16x16x32_f16(pa, vf, oa[ni], 0, 0, 0);
      }
    }
  }

  const int b = bh >> 4, h = bh & 15;
#pragma unroll
  for (int r = 0; r < 4; r++) {
    float lv = l_run[r];
    lv += __shfl_xor(lv, 1, 64);
    lv += __shfl_xor(lv, 2, 64);
    lv += __shfl_xor(lv, 4, 64);
    lv += __shfl_xor(lv, 8, 64);
    const float inv = 1.0f / lv;
    const size_t n = n0 + w * 16 + lg * 4 + r;
    const size_t base = ((size_t)b * NSEQ + n) * CDIM + h * HD;
#pragma unroll
    for (int ni = 0; ni < 4; ni++)
      og[base + ni * 16 + lr] = f16b(oa[ni][r] * inv);
  }
}

// ---------------------------------------------------------------------------
extern "C" void kernel_launch(void* const* d_in, const int* in_sizes, int n_in,
                              void* d_out, int out_size, void* d_ws, size_t ws_size,
                              hipStream_t stream) {
  const float* x      = (const float*)d_in[0];
  const float* wqkv_w = (const float*)d_in[1];
  const float* wqkv_b = (const float*)d_in[2];
  const float* out_w  = (const float*)d_in[3];
  const float* out_b  = (const float*)d_in[4];
  float* out = (float*)d_out;
  u16* ws = (u16*)d_ws;
  float2* cs = (float2*)((char*)d_ws + CS_B);

  rope_table_k<<<dim3((NSEQ * 32 + 255) / 256), 256, 0, stream>>>(cs);
  cvt16_k<<<dim3(8192), 256, 0, stream>>>(x, ws + XH_U, 2097152);
  cvt16_k<<<dim3(3072), 256, 0, stream>>>(wqkv_w, ws + WQH_U, 786432);
  cvt16_k<<<dim3(1024), 256, 0, stream>>>(out_w, ws + OWH_U, 262144);

  // QKV GEMM (fp16, dbuf stage-ahead) + bias + RoPE + fp16 scatter (v^T)
  mgemm_k<1><<<dim3(TC / 128, (NB * NSEQ) / 128), 256, 0, stream>>>(
      ws + XH_U, ws + WQH_U, wqkv_b, nullptr,
      ws + Q_U, ws + K_U, ws + V_U, cs, CDIM);

  // flash attention (fp16 MFMA) -> o fp16 (overwrites x region)
  attn_k<<<dim3(NB * NH, NSEQ / 64), 256, 0, stream>>>(
      ws + Q_U, ws + K_U, ws + V_U, ws + XH_U);

  // out GEMM (fp16, dbuf stage-ahead) + bias -> fp32 d_out
  mgemm_k<0><<<dim3(CDIM / 128, (NB * NSEQ) / 128), 256, 0, stream>>>(
      ws + XH_U, ws + OWH_U, out_b, out,
      nullptr, nullptr, nullptr, cs, CDIM);
}

// Round 7
// 250.889 us; speedup vs baseline: 7.1564x; 1.0041x over previous
//
#include <hip/hip_runtime.h>
#include <math.h>

// Problem constants
#define NB   8
#define NSEQ 1024
#define CDIM 1024
#define NH   16
#define HD   64
#define TC   3072

typedef unsigned short u16;
typedef __attribute__((ext_vector_type(8))) _Float16 f16x8;
typedef __attribute__((ext_vector_type(4))) float f32x4;

// Workspace layout in u16 units (all fp16):
//   q,k : [B][H][N][D] ; vT : [B][H][D][N]
//   xh  : [8192][1024] (x; later overwritten by o)
//   wqh : [3072][1024] ; owh : [1024][1024]
//   cs  : float2[1024][32] RoPE table (byte offset CS_B)
#define Q_U   ((size_t)0)
#define K_U   ((size_t)8388608)
#define V_U   ((size_t)16777216)
#define XH_U  ((size_t)25165824)
#define WQH_U ((size_t)33554432)
#define OWH_U ((size_t)36700160)
#define CS_B  ((size_t)100663296)

__device__ inline u16 f16b(float f) {
  union { _Float16 h; u16 u; } c;
  c.h = (_Float16)f;
  return c.u;
}
__device__ inline void gload16(const u16* g, u16* l) {
  __builtin_amdgcn_global_load_lds(
      (const __attribute__((address_space(1))) void*)g,
      (__attribute__((address_space(3))) void*)l, 16, 0, 0);
}

// ---------------------------------------------------------------------------
__global__ __launch_bounds__(256) void rope_table_k(float2* __restrict__ cs) {
  int idx = blockIdx.x * 256 + threadIdx.x;
  if (idx >= NSEQ * 32) return;
  int n = idx >> 5, p = idx & 31;
  int t = p >> 1;
  int pos = (p & 1) ? (n & 31) : (n >> 5);
  float th = (float)pow(10000.0, -(double)t / 16.0);
  float ang = (float)pos * th;
  cs[idx] = make_float2(cosf(ang), sinf(ang));
}

// ---------------------------------------------------------------------------
// fp32 -> fp16 convert (RNE), float4-vectorized
__global__ __launch_bounds__(256) void cvt16_k(const float* __restrict__ in,
                                               u16* __restrict__ hi, int n4) {
  int i = blockIdx.x * 256 + threadIdx.x;
  if (i >= n4) return;
  float4 v = ((const float4*)in)[i];
  ushort4 h;
  h.x = f16b(v.x); h.y = f16b(v.y); h.z = f16b(v.z); h.w = f16b(v.w);
  ((ushort4*)hi)[i] = h;
}

// ---------------------------------------------------------------------------
// fp16 MFMA GEMM, 4-deep counted-vmcnt pipeline (T3+T4):
//   out[m][c] = A[m][:]·B[c][:] + bias[c]
// 128x128 tile, BK=32, 256 threads (2x2 waves of 64x64), LDS 64 KB (4 stages).
// Steady state: 12 loads in flight; per step ONE raw s_barrier and
// s_waitcnt vmcnt(8) (tile t landed; t+1,t+2 stay in flight across barrier).
// Stage t+3 goes into the buffer tile t-1 used (readers all passed barrier).
// MODE 0: LDS-transposed coalesced float4 store epilogue.
// MODE 1: QKV epilogue (RoPE q/k, fp16; v transposed).
// ---------------------------------------------------------------------------
template <int MODE>
__global__ __launch_bounds__(256, 2) void mgemm_k(
    const u16* __restrict__ A, const u16* __restrict__ B,
    const float* __restrict__ bias, float* __restrict__ outF,
    u16* __restrict__ q, u16* __restrict__ k, u16* __restrict__ v,
    const float2* __restrict__ cs, int K) {
  // 4 stages x (A[128][32] + B[128][32]) u16 = 64 KB
  __shared__ __align__(16) u16 SMEM[32768];

  // XCD-aware bijective swizzle (nwg % 8 == 0 for both call sites)
  const int nwg = gridDim.x * gridDim.y;
  const int bid = blockIdx.y * gridDim.x + blockIdx.x;
  const int swz = (bid & 7) * (nwg >> 3) + (bid >> 3);
  const int bx = swz % gridDim.x;
  const int by = swz / gridDim.x;

  const int t = threadIdx.x;
  const int l = t & 63;
  const int w = t >> 6;
  const int wr = w >> 1, wc = w & 1;
  const int lr = l & 15;
  const int lk = (l >> 4) * 8;
  const int m0 = by * 128, c0 = bx * 128;

  const int srow = t >> 2;
  const int skoff = (t & 3) * 8;
  const int soff = srow * 32 + skoff;
  const u16* agA = A + (size_t)(m0 + srow) * K + skoff;
  const u16* agB = B + (size_t)(c0 + srow) * K + skoff;
  const size_t rstep = (size_t)64 * K;

  f32x4 acc[4][4] = {};
  const int NT = K >> 5;  // 32 K-steps

  auto stage = [&](int kt, int s) {
    const int koff = kt << 5;
    u16* dA = SMEM + s * 8192 + soff;
    u16* dB = SMEM + s * 8192 + 4096 + soff;
    gload16(agA + koff, dA);
    gload16(agA + rstep + koff, dA + 2048);
    gload16(agB + koff, dB);
    gload16(agB + rstep + koff, dB + 2048);
  };
  auto compute = [&](int s) {
    const u16* cA = SMEM + s * 8192;
    const u16* cB = cA + 4096;
    f16x8 bfr[4];
#pragma unroll
    for (int ni = 0; ni < 4; ni++)
      bfr[ni] = *(const f16x8*)(cB + (wc * 64 + ni * 16 + lr) * 32 + lk);
#pragma unroll
    for (int mi = 0; mi < 4; mi++) {
      f16x8 a = *(const f16x8*)(cA + (wr * 64 + mi * 16 + lr) * 32 + lk);
#pragma unroll
      for (int ni = 0; ni < 4; ni++)
        acc[mi][ni] =
            __builtin_amdgcn_mfma_f32_16x16x32_f16(a, bfr[ni], acc[mi][ni], 0, 0, 0);
    }
  };

  // prologue: tiles 0..2 in flight (12 loads)
  stage(0, 0);
  stage(1, 1);
  stage(2, 2);

  for (int kt = 0; kt < NT - 2; ++kt) {
    asm volatile("s_waitcnt vmcnt(8)" ::: "memory");  // tile kt landed
    __builtin_amdgcn_s_barrier();                     // all waves: buf ready,
    __builtin_amdgcn_sched_barrier(0);                // prior readers done
    if (kt + 3 < NT) stage(kt + 3, (kt + 3) & 3);     // overwrite buf of kt-1
    compute(kt & 3);
  }
  asm volatile("s_waitcnt vmcnt(4)" ::: "memory");
  __builtin_amdgcn_s_barrier();
  __builtin_amdgcn_sched_barrier(0);
  compute((NT - 2) & 3);
  asm volatile("s_waitcnt vmcnt(0)" ::: "memory");
  __builtin_amdgcn_s_barrier();
  __builtin_amdgcn_sched_barrier(0);
  compute((NT - 1) & 3);

  if (MODE == 0) {
    // LDS-transposed coalesced epilogue: 4 rounds (one per mi), each
    // 32 rows x 128 cols f32 staged in [32][132] (padded), then per-wave
    // contiguous 512B float4 stores with float4 bias add.
    float* fl = (float*)SMEM;
#pragma unroll
    for (int mi = 0; mi < 4; mi++) {
      __syncthreads();
#pragma unroll
      for (int ni = 0; ni < 4; ni++)
#pragma unroll
        for (int r = 0; r < 4; r++)
          fl[(wr * 16 + (l >> 4) * 4 + r) * 132 + wc * 64 + ni * 16 + lr] =
              acc[mi][ni][r];
      __syncthreads();
#pragma unroll
      for (int p = 0; p < 4; p++) {
        const int sr = (t >> 5) + p * 8;   // 0..31
        const int sc = (t & 31) * 4;
        float4 vv = *(float4*)&fl[sr * 132 + sc];
        float4 bv = *(const float4*)&bias[c0 + sc];
        vv.x += bv.x; vv.y += bv.y; vv.z += bv.z; vv.w += bv.w;
        const int grow = m0 + (sr >> 4) * 64 + mi * 16 + (sr & 15);
        *(float4*)&outF[(size_t)grow * CDIM + c0 + sc] = vv;
      }
    }
  } else {
    const int which = c0 >> 10;  // 0=q 1=k 2=v
    u16* dst = which == 0 ? q : (which == 1 ? k : v);
    const bool dorope = which < 2;
    const int h = ((c0 & 1023) + wc * 64) >> 6;
#pragma unroll
    for (int mi = 0; mi < 4; mi++) {
      const int rbase = m0 + wr * 64 + mi * 16 + (l >> 4) * 4;
#pragma unroll
      for (int ni = 0; ni < 4; ni++) {
        const int d = ni * 16 + lr;
        const float bv = bias[c0 + wc * 64 + d];
#pragma unroll
        for (int r = 0; r < 4; r++) {
          const int m = rbase + r;
          const int b = m >> 10, n = m & 1023;
          float y = acc[mi][ni][r] + bv;
          if (dorope) {
            float yp = __shfl_xor(y, 1, 64);
            float2 csv = cs[n * 32 + (d >> 1)];
            y = (l & 1) ? fmaf(yp, csv.y, y * csv.x)
                        : fmaf(-yp, csv.y, y * csv.x);
            dst[(((size_t)b * NH + h) * NSEQ + n) * HD + d] = f16b(y);
          } else {
            // v: transposed store [bh][d][n]
            dst[(((size_t)b * NH + h) * HD + d) * NSEQ + n] = f16b(y);
          }
        }
      }
    }
  }
}

// ---------------------------------------------------------------------------
// MFMA flash attention, all-fp16 operands. Block = one (b,h) x 64 q-rows;
// 4 waves x 16 rows. Swizzled K [key][d] / V^T [d][key] via pre-swizzled
// global source. Defer-max (THR=8), lane-local l partials, per-wave P (f16).
// ---------------------------------------------------------------------------
__global__ __launch_bounds__(256) void attn_k(const u16* __restrict__ qg0,
                                              const u16* __restrict__ kg0,
                                              const u16* __restrict__ vtg0,
                                              u16* __restrict__ og) {
  __shared__ __align__(16) u16 Ks[4096];     // 64 keys x 64 d (swizzled)
  __shared__ __align__(16) u16 Vt[4096];     // 64 d x 64 keys (swizzled)
  __shared__ __align__(16) u16 Ps[4][1024];  // per-wave 16 q x 64 keys (swz)
  const int t = threadIdx.x;
  const int l = t & 63, w = t >> 6;
  const int lr = l & 15, lg = l >> 4;
  const int bh = blockIdx.x;
  const int n0 = blockIdx.y * 64;

  // Hoist Q A-fragments (row = w*16+lr, k-chunks c*32+lg*8), scale 1/8 (exact)
  f16x8 qf[2];
  {
    const u16* qp = qg0 + ((size_t)bh * NSEQ + n0 + w * 16 + lr) * HD + lg * 8;
#pragma unroll
    for (int c = 0; c < 2; c++) {
      f16x8 raw = *(const f16x8*)(qp + c * 32);
#pragma unroll
      for (int j = 0; j < 8; j++) raw[j] = raw[j] * (_Float16)0.125f;
      qf[c] = raw;
    }
  }

  const int r0 = t >> 3, b0 = (t & 7) ^ (r0 & 7);
  const int r1 = (256 + t) >> 3, b1 = ((256 + t) & 7) ^ (r1 & 7);
  const u16* kgb = kg0 + (size_t)bh * NSEQ * HD;
  const u16* vgb = vtg0 + (size_t)bh * HD * NSEQ;
  const u16* kga0 = kgb + r0 * 64 + b0 * 8;
  const u16* kga1 = kgb + r1 * 64 + b1 * 8;
  const u16* vga0 = vgb + r0 * 1024 + b0 * 8;
  const u16* vga1 = vgb + r1 * 1024 + b1 * 8;
  u16* ksd0 = Ks + (size_t)t * 8;
  u16* ksd1 = Ks + (size_t)(256 + t) * 8;
  u16* vtd0 = Vt + (size_t)t * 8;
  u16* vtd1 = Vt + (size_t)(256 + t) * 8;

  float m_run[4], l_run[4];
  f32x4 oa[4] = {};
#pragma unroll
  for (int r = 0; r < 4; r++) { m_run[r] = -INFINITY; l_run[r] = 0.f; }

  for (int kt = 0; kt < 16; kt++) {
    __syncthreads();  // prior tile's LDS reads complete
    gload16(kga0 + kt * 4096, ksd0);
    gload16(kga1 + kt * 4096, ksd1);
    gload16(vga0 + kt * 64, vtd0);
    gload16(vga1 + kt * 64, vtd1);
    __syncthreads();  // staging drained

    // S = Q K^T
    f32x4 s[4] = {};
#pragma unroll
    for (int c = 0; c < 2; c++) {
#pragma unroll
      for (int ni = 0; ni < 4; ni++) {
        const int kr = ni * 16 + lr;
        f16x8 kf = *(const f16x8*)&Ks[kr * 64 + (((c * 4 + lg) ^ (kr & 7)) * 8)];
        s[ni] = __builtin_amdgcn_mfma_f32_16x16x32_f16(qf[c], kf, s[ni], 0, 0, 0);
      }
    }

    // Row maxima (shfl over the 16 col-lanes)
    float tm[4];
#pragma unroll
    for (int r = 0; r < 4; r++) {
      float m1 = fmaxf(fmaxf(s[0][r], s[1][r]), fmaxf(s[2][r], s[3][r]));
      m1 = fmaxf(m1, __shfl_xor(m1, 1, 64));
      m1 = fmaxf(m1, __shfl_xor(m1, 2, 64));
      m1 = fmaxf(m1, __shfl_xor(m1, 4, 64));
      m1 = fmaxf(m1, __shfl_xor(m1, 8, 64));
      tm[r] = m1;
    }
    // Defer-max: rescale only if some row grew past THR=8 (wave-uniform)
    const bool ok = (tm[0] <= m_run[0] + 8.f) && (tm[1] <= m_run[1] + 8.f) &&
                    (tm[2] <= m_run[2] + 8.f) && (tm[3] <= m_run[3] + 8.f);
    if (!__all(ok)) {
#pragma unroll
      for (int r = 0; r < 4; r++) {
        const float mn = fmaxf(m_run[r], tm[r]);
        const float fs = __expf(m_run[r] - mn);
        m_run[r] = mn;
        l_run[r] *= fs;
#pragma unroll
        for (int ni = 0; ni < 4; ni++) oa[ni][r] *= fs;
      }
    }
    // P = exp(S - m) (<= e^8); lane-local l partials; store P fp16 (own wave)
#pragma unroll
    for (int r = 0; r < 4; r++) {
      float p[4], ps = 0.f;
#pragma unroll
      for (int ni = 0; ni < 4; ni++) { p[ni] = __expf(s[ni][r] - m_run[r]); ps += p[ni]; }
      l_run[r] += ps;
      const int prow = lg * 4 + r;
      const int sw = prow & 7;
#pragma unroll
      for (int ni = 0; ni < 4; ni++)
        Ps[w][prow * 64 + (((ni * 2 + (lr >> 3)) ^ sw) * 8) + (lr & 7)] =
            f16b(p[ni]);
    }
    // No barrier: Ps is read only by the writing wave (same-wave DS in-order)

    // O += P V
#pragma unroll
    for (int c = 0; c < 2; c++) {
      f16x8 pa = *(const f16x8*)&Ps[w][lr * 64 + (((c * 4 + lg) ^ (lr & 7)) * 8)];
#pragma unroll
      for (int ni = 0; ni < 4; ni++) {
        const int dr = ni * 16 + lr;
        f16x8 vf = *(const f16x8*)&Vt[dr * 64 + (((c * 4 + lg) ^ (dr & 7)) * 8)];
        oa[ni] = __builtin_amdgcn_mfma_f32_16x16x32_f16(pa, vf, oa[ni], 0, 0, 0);
      }
    }
  }

  const int b = bh >> 4, h = bh & 15;
#pragma unroll
  for (int r = 0; r < 4; r++) {
    float lv = l_run[r];
    lv += __shfl_xor(lv, 1, 64);
    lv += __shfl_xor(lv, 2, 64);
    lv += __shfl_xor(lv, 4, 64);
    lv += __shfl_xor(lv, 8, 64);
    const float inv = 1.0f / lv;
    const size_t n = n0 + w * 16 + lg * 4 + r;
    const size_t base = ((size_t)b * NSEQ + n) * CDIM + h * HD;
#pragma unroll
    for (int ni = 0; ni < 4; ni++)
      og[base + ni * 16 + lr] = f16b(oa[ni][r] * inv);
  }
}

// ---------------------------------------------------------------------------
extern "C" void kernel_launch(void* const* d_in, const int* in_sizes, int n_in,
                              void* d_out, int out_size, void* d_ws, size_t ws_size,
                              hipStream_t stream) {
  const float* x      = (const float*)d_in[0];
  const float* wqkv_w = (const float*)d_in[1];
  const float* wqkv_b = (const float*)d_in[2];
  const float* out_w  = (const float*)d_in[3];
  const float* out_b  = (const float*)d_in[4];
  float* out = (float*)d_out;
  u16* ws = (u16*)d_ws;
  float2* cs = (float2*)((char*)d_ws + CS_B);

  rope_table_k<<<dim3((NSEQ * 32 + 255) / 256), 256, 0, stream>>>(cs);
  cvt16_k<<<dim3(8192), 256, 0, stream>>>(x, ws + XH_U, 2097152);
  cvt16_k<<<dim3(3072), 256, 0, stream>>>(wqkv_w, ws + WQH_U, 786432);
  cvt16_k<<<dim3(1024), 256, 0, stream>>>(out_w, ws + OWH_U, 262144);

  // QKV GEMM (fp16, 4-deep counted-vmcnt) + bias + RoPE + fp16 scatter (v^T)
  mgemm_k<1><<<dim3(TC / 128, (NB * NSEQ) / 128), 256, 0, stream>>>(
      ws + XH_U, ws + WQH_U, wqkv_b, nullptr,
      ws + Q_U, ws + K_U, ws + V_U, cs, CDIM);

  // flash attention (fp16 MFMA) -> o fp16 (overwrites x region)
  attn_k<<<dim3(NB * NH, NSEQ / 64), 256, 0, stream>>>(
      ws + Q_U, ws + K_U, ws + V_U, ws + XH_U);

  // out GEMM (fp16, 4-deep counted-vmcnt) + bias -> fp32 d_out (coalesced)
  mgemm_k<0><<<dim3(CDIM / 128, (NB * NSEQ) / 128), 256, 0, stream>>>(
      ws + XH_U, ws + OWH_U, out_b, out,
      nullptr, nullptr, nullptr, cs, CDIM);
}